// Round 1
// baseline (4548.661 us; speedup 1.0000x reference)
//
#include <hip/hip_runtime.h>
#include <hip/hip_bf16.h>

#define DMODEL 512
#define NB 8
#define VOCABSZ 2048
#define MEL 80
#define DIN 1024
#define NSTATE 16
#define DTRANK 32
#define BATCH 4
#define TIN 2048
#define LL1 1024
#define LSEQ 512
#define MROWS (BATCH*LSEQ)    // 2048
#define M1ROWS (BATCH*LL1)    // 4096

__device__ __forceinline__ float gelu_exact(float v) {
    return 0.5f * v * (1.0f + erff(v * 0.70710678118654752f));
}
__device__ __forceinline__ float silu_f(float v) {
    return v / (1.0f + __expf(-v));
}
__device__ __forceinline__ float softplus_f(float v) {
    return v > 20.f ? v : log1pf(__expf(v));
}

// ---------------------------------------------------------------------------
// Generic fp32 tiled GEMM.  C[M,N] = epi(A[M,K] @ B + bias)
// BT==0: B is (K,N) row-major with ldb=N.  BT==1: B is (N,K) row-major, ldb=K.
// EPI: 0 none, 1 +bias, 2 gelu(+bias), 3 softplus(+bias), 4 += C (residual)
// Requires M%64==0, N%64==0, K%16==0 (true for every call here).
// ---------------------------------------------------------------------------
template<int BT, int EPI>
__global__ __launch_bounds__(256) void gemm_f32(
    const float* __restrict__ A, int lda,
    const float* __restrict__ B, int ldb,
    const float* __restrict__ bias,
    float* __restrict__ C, int ldc,
    int M, int N, int K)
{
    __shared__ __align__(16) float As[16][68];
    __shared__ __align__(16) float Bs[16][68];
    const int tid = threadIdx.x;
    const int m0 = blockIdx.y * 64;
    const int n0 = blockIdx.x * 64;
    const int tn = tid & 15, tm = tid >> 4;

    float acc[4][4];
#pragma unroll
    for (int i = 0; i < 4; i++)
#pragma unroll
        for (int j = 0; j < 4; j++) acc[i][j] = 0.f;

    const int akk = tid & 15;   // k within tile
    const int am  = tid >> 4;   // row group

    for (int kt = 0; kt < K; kt += 16) {
        // stage A tile transposed: As[kk][m]
#pragma unroll
        for (int r = 0; r < 4; ++r) {
            int m = am + 16 * r;
            As[akk][m] = A[(size_t)(m0 + m) * lda + kt + akk];
        }
        if (BT == 0) {
            int nn = tid & 63;
            int kk0 = tid >> 6;
#pragma unroll
            for (int r = 0; r < 4; ++r) {
                int kk = kk0 * 4 + r;
                Bs[kk][nn] = B[(size_t)(kt + kk) * ldb + n0 + nn];
            }
        } else {
#pragma unroll
            for (int r = 0; r < 4; ++r) {
                int nn = am + 16 * r;
                Bs[akk][nn] = B[(size_t)(n0 + nn) * ldb + kt + akk];
            }
        }
        __syncthreads();
#pragma unroll
        for (int kk = 0; kk < 16; ++kk) {
            const float4 av = *reinterpret_cast<const float4*>(&As[kk][tm * 4]);
            const float4 bv = *reinterpret_cast<const float4*>(&Bs[kk][tn * 4]);
            const float a_[4] = {av.x, av.y, av.z, av.w};
            const float b_[4] = {bv.x, bv.y, bv.z, bv.w};
#pragma unroll
            for (int i = 0; i < 4; i++)
#pragma unroll
                for (int j = 0; j < 4; j++)
                    acc[i][j] = fmaf(a_[i], b_[j], acc[i][j]);
        }
        __syncthreads();
    }

#pragma unroll
    for (int i = 0; i < 4; i++) {
        int m = m0 + tm * 4 + i;
#pragma unroll
        for (int j = 0; j < 4; j++) {
            int n = n0 + tn * 4 + j;
            float v = acc[i][j];
            if (EPI == 1)      v += bias[n];
            else if (EPI == 2) v = gelu_exact(v + bias[n]);
            else if (EPI == 3) v = softplus_f(v + bias[n]);
            else if (EPI == 4) v += C[(size_t)m * ldc + n];
            C[(size_t)m * ldc + n] = v;
        }
    }
}

// im2col for conv1: out[(b*L1+l1)*240 + ci*3+k] = feats[b, 2*l1-1+k, ci]
__global__ void im2col1_k(const float* __restrict__ feats, float* __restrict__ out) {
    int idx = blockIdx.x * 256 + threadIdx.x;      // M1ROWS*MEL
    if (idx >= M1ROWS * MEL) return;
    int ci = idx % MEL;
    int m  = idx / MEL;
    int l1 = m & (LL1 - 1);
    int b  = m >> 10;
#pragma unroll
    for (int k = 0; k < 3; k++) {
        int t = 2 * l1 - 1 + k;
        float v = (t >= 0 && t < TIN) ? feats[((size_t)b * TIN + t) * MEL + ci] : 0.f;
        out[(size_t)m * 240 + ci * 3 + k] = v;
    }
}

// im2col for conv2: out[(b*L+l)*1536 + ci*3+k] = y1[(b*L1 + 2*l-1+k)*512 + ci]
__global__ void im2col2_k(const float* __restrict__ y1, float* __restrict__ out) {
    int idx = blockIdx.x * 256 + threadIdx.x;      // MROWS*512
    int ci = idx & 511;
    int m  = idx >> 9;
    int l  = m & (LSEQ - 1);
    int b  = m >> 9;
#pragma unroll
    for (int k = 0; k < 3; k++) {
        int t = 2 * l - 1 + k;
        float v = (t >= 0 && t < LL1) ? y1[((size_t)b * LL1 + t) * 512 + ci] : 0.f;
        out[(size_t)m * 1536 + ci * 3 + k] = v;
    }
}

// RMSNorm: one block per row of 512
__global__ __launch_bounds__(256) void rmsnorm_k(const float* __restrict__ x,
                                                 const float* __restrict__ nw,
                                                 float* __restrict__ xn) {
    int m = blockIdx.x;
    int tid = threadIdx.x;
    const float2 v = *reinterpret_cast<const float2*>(&x[(size_t)m * DMODEL + tid * 2]);
    float ss = v.x * v.x + v.y * v.y;
#pragma unroll
    for (int o = 32; o > 0; o >>= 1) ss += __shfl_down(ss, o);
    __shared__ float sred[4];
    __shared__ float sscale;
    if ((tid & 63) == 0) sred[tid >> 6] = ss;
    __syncthreads();
    if (tid == 0) {
        float tot = sred[0] + sred[1] + sred[2] + sred[3];
        sscale = rsqrtf(tot / 512.f + 1e-5f);
    }
    __syncthreads();
    float sc = sscale;
    float2 o2;
    o2.x = v.x * sc * nw[tid * 2];
    o2.y = v.y * sc * nw[tid * 2 + 1];
    *reinterpret_cast<float2*>(&xn[(size_t)m * DMODEL + tid * 2]) = o2;
}

// causal depthwise conv (K=4) + bias + SiLU.  xz holds [xs | z] rows of 2048.
__global__ __launch_bounds__(256) void dwconv_silu_k(const float* __restrict__ xz,
                                                     const float* __restrict__ cw,
                                                     const float* __restrict__ cb,
                                                     float* __restrict__ xs) {
    int d = blockIdx.x * 256 + threadIdx.x;    // 0..1023
    int m = blockIdx.y;                        // 0..2047
    int l = m & (LSEQ - 1);
    int b = m >> 9;
    float acc = cb[d];
    const float4 w4 = *reinterpret_cast<const float4*>(&cw[d * 4]);
    const float wk[4] = {w4.x, w4.y, w4.z, w4.w};
#pragma unroll
    for (int k = 0; k < 4; k++) {
        int t = l - 3 + k;
        if (t >= 0) acc += wk[k] * xz[((size_t)(b * LSEQ + t)) * (2 * DIN) + d];
    }
    xs[(size_t)m * DIN + d] = silu_f(acc);
}

// Selective-scan. thread = (b fixed per block.y, d, 4-state group j).
// B/C for all 512 timesteps preloaded in LDS (64KB). Fuses +xs*D and *silu(z).
__global__ __launch_bounds__(256) void scan_k(
    const float* __restrict__ delta, const float* __restrict__ xs,
    const float* __restrict__ xdb, const float* __restrict__ xz,
    const float* __restrict__ alog, const float* __restrict__ dsk,
    float* __restrict__ y)
{
    __shared__ float s_bc[LSEQ * 32];          // 64 KB
    const int tid = threadIdx.x;
    const int b = blockIdx.y;
    const int j = tid & 3;
    const int dsub = tid >> 2;
    const int d = blockIdx.x * 64 + dsub;

    for (int idx = tid; idx < LSEQ * 32; idx += 256) {
        int t = idx >> 5, c = idx & 31;
        s_bc[idx] = xdb[((size_t)(b * LSEQ + t)) * 64 + 32 + c];
    }
    __syncthreads();

    float a[4], h[4];
#pragma unroll
    for (int nj = 0; nj < 4; nj++) {
        a[nj] = -__expf(alog[(size_t)d * NSTATE + j * 4 + nj]);
        h[nj] = 0.f;
    }
    const float dskv = dsk[d];
    const size_t base = (size_t)b * LSEQ;

    for (int t = 0; t < LSEQ; t++) {
        const size_t row = base + t;
        const float dl = delta[row * DIN + d];
        const float xv = xs[row * DIN + d];
        float yv = 0.f;
#pragma unroll
        for (int nj = 0; nj < 4; nj++) {
            float bn = s_bc[t * 32 + j * 4 + nj];
            float cn = s_bc[t * 32 + 16 + j * 4 + nj];
            float dA = __expf(dl * a[nj]);
            h[nj] = fmaf(dA, h[nj], dl * bn * xv);
            yv = fmaf(h[nj], cn, yv);
        }
        yv += __shfl_xor(yv, 1);
        yv += __shfl_xor(yv, 2);
        if (j == 0) {
            float zv = xz[row * (2 * DIN) + DIN + d];
            y[row * DIN + d] = (yv + xv * dskv) * silu_f(zv);
        }
    }
}

__global__ void lens_k(const int* __restrict__ feat_lens, float* __restrict__ out) {
    int b = threadIdx.x;
    if (b < BATCH) {
        int v = feat_lens[b] / 4;
        if (v < 1) v = 1;
        out[b] = (float)v;
    }
}

extern "C" void kernel_launch(void* const* d_in, const int* in_sizes, int n_in,
                              void* d_out, int out_size, void* d_ws, size_t ws_size,
                              hipStream_t stream)
{
    const float* feats = (const float*)d_in[0];
    const int*   flens = (const int*)  d_in[1];
    const float* c1w = (const float*)d_in[2];
    const float* c1b = (const float*)d_in[3];
    const float* c2w = (const float*)d_in[4];
    const float* c2b = (const float*)d_in[5];
    const float* nw  = (const float*)d_in[6];
    const float* ipw = (const float*)d_in[7];
    const float* cw  = (const float*)d_in[8];
    const float* cb  = (const float*)d_in[9];
    const float* xpw = (const float*)d_in[10];
    const float* dpw = (const float*)d_in[11];
    const float* dpb = (const float*)d_in[12];
    const float* alog= (const float*)d_in[13];
    const float* dskp= (const float*)d_in[14];
    const float* opw = (const float*)d_in[15];
    const float* hw  = (const float*)d_in[16];
    const float* hb  = (const float*)d_in[17];

    float* ws  = (float*)d_ws;
    float* XZ  = ws;                  // 4,194,304 f  (xz / im2col1 / im2col2)
    float* X   = ws + 4194304;        // 1,048,576 f
    float* XN  = X   + 1048576;       // 1,048,576 f
    float* XS  = XN  + 1048576;       // 2,097,152 f
    float* DEL = XS  + 2097152;       // 2,097,152 f  (also Y1 during frontend)
    float* Y   = DEL + 2097152;       // 2,097,152 f
    float* XDB = Y   + 2097152;       // 131,072 f
    float* Y1  = DEL;                 // frontend-only alias
    float* logits = (float*)d_out;

    // ---------------- frontend ----------------
    im2col1_k<<<1280, 256, 0, stream>>>(feats, XZ);
    gemm_f32<1, 2><<<dim3(512 / 64, M1ROWS / 64), 256, 0, stream>>>(
        XZ, 240, c1w, 240, c1b, Y1, 512, M1ROWS, 512, 240);
    im2col2_k<<<(MROWS * 512) / 256, 256, 0, stream>>>(Y1, XZ);
    gemm_f32<1, 2><<<dim3(512 / 64, MROWS / 64), 256, 0, stream>>>(
        XZ, 1536, c2w, 1536, c2b, X, 512, MROWS, 512, 1536);

    // ---------------- mamba blocks ----------------
    for (int blk = 0; blk < NB; ++blk) {
        rmsnorm_k<<<MROWS, 256, 0, stream>>>(X, nw + blk * DMODEL, XN);
        gemm_f32<0, 0><<<dim3(2048 / 64, MROWS / 64), 256, 0, stream>>>(
            XN, 512, ipw + (size_t)blk * 512 * 2048, 2048, nullptr,
            XZ, 2048, MROWS, 2048, 512);
        dwconv_silu_k<<<dim3(4, MROWS), 256, 0, stream>>>(
            XZ, cw + blk * DIN * 4, cb + blk * DIN, XS);
        gemm_f32<0, 0><<<dim3(64 / 64, MROWS / 64), 256, 0, stream>>>(
            XS, 1024, xpw + (size_t)blk * 1024 * 64, 64, nullptr,
            XDB, 64, MROWS, 64, 1024);
        gemm_f32<0, 3><<<dim3(1024 / 64, MROWS / 64), 256, 0, stream>>>(
            XDB, 64, dpw + (size_t)blk * 32 * 1024, 1024, dpb + blk * DIN,
            DEL, 1024, MROWS, 1024, 32);
        scan_k<<<dim3(16, BATCH), 256, 0, stream>>>(
            DEL, XS, XDB, XZ, alog + (size_t)blk * DIN * NSTATE,
            dskp + blk * DIN, Y);
        gemm_f32<0, 4><<<dim3(512 / 64, MROWS / 64), 256, 0, stream>>>(
            Y, 1024, opw + (size_t)blk * 1024 * 512, 512, nullptr,
            X, 512, MROWS, 512, 1024);
    }

    // ---------------- head ----------------
    gemm_f32<0, 1><<<dim3(2048 / 64, MROWS / 64), 256, 0, stream>>>(
        X, 512, hw, 2048, hb, logits, 2048, MROWS, 2048, 512);
    lens_k<<<1, 64, 0, stream>>>(flens, logits + (size_t)MROWS * VOCABSZ);
}

// Round 2
// 2013.152 us; speedup vs baseline: 2.2595x; 2.2595x over previous
//
#include <hip/hip_runtime.h>
#include <hip/hip_bf16.h>

#define DMODEL 512
#define NB 8
#define VOCABSZ 2048
#define MEL 80
#define DIN 1024
#define NSTATE 16
#define DTRANK 32
#define BATCH 4
#define TIN 2048
#define LL1 1024
#define LSEQ 512
#define MROWS (BATCH*LSEQ)    // 2048
#define M1ROWS (BATCH*LL1)    // 4096
#define NCHUNK 16
#define LCHUNK 32             // NCHUNK*LCHUNK == LSEQ

__device__ __forceinline__ float gelu_exact(float v) {
    return 0.5f * v * (1.0f + erff(v * 0.70710678118654752f));
}
__device__ __forceinline__ float silu_f(float v) {
    return v / (1.0f + __expf(-v));
}
__device__ __forceinline__ float softplus_f(float v) {
    return v > 20.f ? v : log1pf(__expf(v));
}

// ---------------------------------------------------------------------------
// Generic fp32 tiled GEMM.  C[M,N] = epi(A[M,K] @ B + bias)
// BT==0: B is (K,N) row-major with ldb=N.  BT==1: B is (N,K) row-major, ldb=K.
// EPI: 0 none, 1 +bias, 2 gelu(+bias), 3 softplus(+bias), 4 += C (residual)
// ---------------------------------------------------------------------------
template<int BT, int EPI>
__global__ __launch_bounds__(256) void gemm_f32(
    const float* __restrict__ A, int lda,
    const float* __restrict__ B, int ldb,
    const float* __restrict__ bias,
    float* __restrict__ C, int ldc,
    int M, int N, int K)
{
    __shared__ __align__(16) float As[16][68];
    __shared__ __align__(16) float Bs[16][68];
    const int tid = threadIdx.x;
    const int m0 = blockIdx.y * 64;
    const int n0 = blockIdx.x * 64;
    const int tn = tid & 15, tm = tid >> 4;

    float acc[4][4];
#pragma unroll
    for (int i = 0; i < 4; i++)
#pragma unroll
        for (int j = 0; j < 4; j++) acc[i][j] = 0.f;

    const int akk = tid & 15;   // k within tile
    const int am  = tid >> 4;   // row group

    for (int kt = 0; kt < K; kt += 16) {
#pragma unroll
        for (int r = 0; r < 4; ++r) {
            int m = am + 16 * r;
            As[akk][m] = A[(size_t)(m0 + m) * lda + kt + akk];
        }
        if (BT == 0) {
            int nn = tid & 63;
            int kk0 = tid >> 6;
#pragma unroll
            for (int r = 0; r < 4; ++r) {
                int kk = kk0 * 4 + r;
                Bs[kk][nn] = B[(size_t)(kt + kk) * ldb + n0 + nn];
            }
        } else {
#pragma unroll
            for (int r = 0; r < 4; ++r) {
                int nn = am + 16 * r;
                Bs[akk][nn] = B[(size_t)(n0 + nn) * ldb + kt + akk];
            }
        }
        __syncthreads();
#pragma unroll
        for (int kk = 0; kk < 16; ++kk) {
            const float4 av = *reinterpret_cast<const float4*>(&As[kk][tm * 4]);
            const float4 bv = *reinterpret_cast<const float4*>(&Bs[kk][tn * 4]);
            const float a_[4] = {av.x, av.y, av.z, av.w};
            const float b_[4] = {bv.x, bv.y, bv.z, bv.w};
#pragma unroll
            for (int i = 0; i < 4; i++)
#pragma unroll
                for (int j = 0; j < 4; j++)
                    acc[i][j] = fmaf(a_[i], b_[j], acc[i][j]);
        }
        __syncthreads();
    }

#pragma unroll
    for (int i = 0; i < 4; i++) {
        int m = m0 + tm * 4 + i;
#pragma unroll
        for (int j = 0; j < 4; j++) {
            int n = n0 + tn * 4 + j;
            float v = acc[i][j];
            if (EPI == 1)      v += bias[n];
            else if (EPI == 2) v = gelu_exact(v + bias[n]);
            else if (EPI == 3) v = softplus_f(v + bias[n]);
            else if (EPI == 4) v += C[(size_t)m * ldc + n];
            C[(size_t)m * ldc + n] = v;
        }
    }
}

// im2col for conv1
__global__ void im2col1_k(const float* __restrict__ feats, float* __restrict__ out) {
    int idx = blockIdx.x * 256 + threadIdx.x;
    if (idx >= M1ROWS * MEL) return;
    int ci = idx % MEL;
    int m  = idx / MEL;
    int l1 = m & (LL1 - 1);
    int b  = m >> 10;
#pragma unroll
    for (int k = 0; k < 3; k++) {
        int t = 2 * l1 - 1 + k;
        float v = (t >= 0 && t < TIN) ? feats[((size_t)b * TIN + t) * MEL + ci] : 0.f;
        out[(size_t)m * 240 + ci * 3 + k] = v;
    }
}

// im2col for conv2
__global__ void im2col2_k(const float* __restrict__ y1, float* __restrict__ out) {
    int idx = blockIdx.x * 256 + threadIdx.x;
    int ci = idx & 511;
    int m  = idx >> 9;
    int l  = m & (LSEQ - 1);
    int b  = m >> 9;
#pragma unroll
    for (int k = 0; k < 3; k++) {
        int t = 2 * l - 1 + k;
        float v = (t >= 0 && t < LL1) ? y1[((size_t)b * LL1 + t) * 512 + ci] : 0.f;
        out[(size_t)m * 1536 + ci * 3 + k] = v;
    }
}

// RMSNorm: one block per row of 512
__global__ __launch_bounds__(256) void rmsnorm_k(const float* __restrict__ x,
                                                 const float* __restrict__ nw,
                                                 float* __restrict__ xn) {
    int m = blockIdx.x;
    int tid = threadIdx.x;
    const float2 v = *reinterpret_cast<const float2*>(&x[(size_t)m * DMODEL + tid * 2]);
    float ss = v.x * v.x + v.y * v.y;
#pragma unroll
    for (int o = 32; o > 0; o >>= 1) ss += __shfl_down(ss, o);
    __shared__ float sred[4];
    __shared__ float sscale;
    if ((tid & 63) == 0) sred[tid >> 6] = ss;
    __syncthreads();
    if (tid == 0) {
        float tot = sred[0] + sred[1] + sred[2] + sred[3];
        sscale = rsqrtf(tot / 512.f + 1e-5f);
    }
    __syncthreads();
    float sc = sscale;
    float2 o2;
    o2.x = v.x * sc * nw[tid * 2];
    o2.y = v.y * sc * nw[tid * 2 + 1];
    *reinterpret_cast<float2*>(&xn[(size_t)m * DMODEL + tid * 2]) = o2;
}

// causal depthwise conv (K=4) + bias + SiLU
__global__ __launch_bounds__(256) void dwconv_silu_k(const float* __restrict__ xz,
                                                     const float* __restrict__ cw,
                                                     const float* __restrict__ cb,
                                                     float* __restrict__ xs) {
    int d = blockIdx.x * 256 + threadIdx.x;
    int m = blockIdx.y;
    int l = m & (LSEQ - 1);
    int b = m >> 9;
    float acc = cb[d];
    const float4 w4 = *reinterpret_cast<const float4*>(&cw[d * 4]);
    const float wk[4] = {w4.x, w4.y, w4.z, w4.w};
#pragma unroll
    for (int k = 0; k < 4; k++) {
        int t = l - 3 + k;
        if (t >= 0) acc += wk[k] * xz[((size_t)(b * LSEQ + t)) * (2 * DIN) + d];
    }
    xs[(size_t)m * DIN + d] = silu_f(acc);
}

// ---------------------------------------------------------------------------
// Chunked parallel scan.
// Channel = (b,d,n); h_t = exp(delta*A)*h_{t-1} + delta*B_t*x_t.
// PASS 0: per (b, chunk, 64 d's) block, local scan from h=0; emit
//         P = exp(a * sum(delta)) and q = local final h, layout [b][c][d][n].
// PASS 1: seeded with hin; emits y with fused +xs*D and *silu(z).
// Block: 256 thr = 64 d  x  4 n-groups (4 states each).
// ---------------------------------------------------------------------------
template<int PASS>
__global__ __launch_bounds__(256) void scan_chunk_k(
    const float* __restrict__ delta, const float* __restrict__ xs,
    const float* __restrict__ xdb, const float* __restrict__ xz,
    const float* __restrict__ alog, const float* __restrict__ dsk,
    const float* __restrict__ hin,
    float* __restrict__ Pout, float* __restrict__ Qout,
    float* __restrict__ y)
{
    __shared__ float s_bc[LCHUNK * 32];   // B|C, 4 KB
    __shared__ float s_dl[LCHUNK * 64];   // 8 KB
    __shared__ float s_xs[LCHUNK * 64];   // 8 KB
    __shared__ float s_z [PASS ? LCHUNK * 64 : 1];

    const int tid  = threadIdx.x;
    const int j    = tid & 3;
    const int dsub = tid >> 2;
    const int d0   = blockIdx.x * 64;
    const int c    = blockIdx.y;
    const int b    = blockIdx.z;
    const int d    = d0 + dsub;
    const size_t rbase = (size_t)b * LSEQ + c * LCHUNK;

    for (int idx = tid; idx < LCHUNK * 32; idx += 256) {
        int t = idx >> 5, cc = idx & 31;
        s_bc[idx] = xdb[(rbase + t) * 64 + 32 + cc];
    }
    for (int idx = tid; idx < LCHUNK * 64; idx += 256) {
        int t = idx >> 6, dd = idx & 63;
        s_dl[idx] = delta[(rbase + t) * DIN + d0 + dd];
        s_xs[idx] = xs[(rbase + t) * DIN + d0 + dd];
        if (PASS) s_z[idx] = xz[(rbase + t) * (2 * DIN) + DIN + d0 + dd];
    }
    __syncthreads();

    float a[4], h[4];
#pragma unroll
    for (int nj = 0; nj < 4; nj++)
        a[nj] = -__expf(alog[(size_t)d * NSTATE + j * 4 + nj]);

    const size_t chbase = ((size_t)(b * NCHUNK + c) * DIN + d) * NSTATE + j * 4;
    if (PASS) {
        const float4 h4 = *reinterpret_cast<const float4*>(&hin[chbase]);
        h[0] = h4.x; h[1] = h4.y; h[2] = h4.z; h[3] = h4.w;
    } else {
        h[0] = h[1] = h[2] = h[3] = 0.f;
    }
    const float dskv = PASS ? dsk[d] : 0.f;
    float sdl = 0.f;

    for (int t = 0; t < LCHUNK; t++) {
        const float dl = s_dl[t * 64 + dsub];
        const float xv = s_xs[t * 64 + dsub];
        const float dlx = dl * xv;
        if (!PASS) sdl += dl;
        float yv = 0.f;
#pragma unroll
        for (int nj = 0; nj < 4; nj++) {
            const float bn = s_bc[t * 32 + j * 4 + nj];
            const float dA = __expf(dl * a[nj]);
            h[nj] = fmaf(dA, h[nj], dlx * bn);
            if (PASS) {
                const float cn = s_bc[t * 32 + 16 + j * 4 + nj];
                yv = fmaf(h[nj], cn, yv);
            }
        }
        if (PASS) {
            yv += __shfl_xor(yv, 1);
            yv += __shfl_xor(yv, 2);
            if (j == 0) {
                const float zv = s_z[t * 64 + dsub];
                y[(rbase + t) * DIN + d] = (yv + xv * dskv) * silu_f(zv);
            }
        }
    }

    if (!PASS) {
        float4 Pv, Qv;
        Pv.x = __expf(a[0] * sdl); Pv.y = __expf(a[1] * sdl);
        Pv.z = __expf(a[2] * sdl); Pv.w = __expf(a[3] * sdl);
        Qv.x = h[0]; Qv.y = h[1]; Qv.z = h[2]; Qv.w = h[3];
        *reinterpret_cast<float4*>(&Pout[chbase]) = Pv;
        *reinterpret_cast<float4*>(&Qout[chbase]) = Qv;
    }
}

// Combine pass: per channel, hin[c] = P[c-1]*hin[c-1] + q[c-1]; in-place over Q.
__global__ __launch_bounds__(256) void scan_mid_k(const float* __restrict__ P,
                                                  float* __restrict__ Q) {
    const int tid = blockIdx.x * 256 + threadIdx.x;   // 0..65535
    const int b  = tid >> 14;
    const int dn = tid & 16383;
    const size_t base = (size_t)b * (NCHUNK * DIN * NSTATE) + dn;
    float p[NCHUNK], q[NCHUNK];
#pragma unroll
    for (int c = 0; c < NCHUNK; c++) {
        p[c] = P[base + (size_t)c * (DIN * NSTATE)];
        q[c] = Q[base + (size_t)c * (DIN * NSTATE)];
    }
    float h = 0.f;
    Q[base] = 0.f;
#pragma unroll
    for (int c = 1; c < NCHUNK; c++) {
        h = fmaf(p[c - 1], h, q[c - 1]);
        Q[base + (size_t)c * (DIN * NSTATE)] = h;
    }
}

__global__ void lens_k(const int* __restrict__ feat_lens, float* __restrict__ out) {
    int b = threadIdx.x;
    if (b < BATCH) {
        int v = feat_lens[b] / 4;
        if (v < 1) v = 1;
        out[b] = (float)v;
    }
}

extern "C" void kernel_launch(void* const* d_in, const int* in_sizes, int n_in,
                              void* d_out, int out_size, void* d_ws, size_t ws_size,
                              hipStream_t stream)
{
    const float* feats = (const float*)d_in[0];
    const int*   flens = (const int*)  d_in[1];
    const float* c1w = (const float*)d_in[2];
    const float* c1b = (const float*)d_in[3];
    const float* c2w = (const float*)d_in[4];
    const float* c2b = (const float*)d_in[5];
    const float* nw  = (const float*)d_in[6];
    const float* ipw = (const float*)d_in[7];
    const float* cw  = (const float*)d_in[8];
    const float* cb  = (const float*)d_in[9];
    const float* xpw = (const float*)d_in[10];
    const float* dpw = (const float*)d_in[11];
    const float* dpb = (const float*)d_in[12];
    const float* alog= (const float*)d_in[13];
    const float* dskp= (const float*)d_in[14];
    const float* opw = (const float*)d_in[15];
    const float* hw  = (const float*)d_in[16];
    const float* hb  = (const float*)d_in[17];

    float* ws  = (float*)d_ws;
    float* XZ  = ws;                  // 4,194,304 f  (xz / im2col1 / im2col2)
    float* X   = ws + 4194304;        // 1,048,576 f
    float* XN  = X   + 1048576;       // 1,048,576 f  (also P between in_proj & next rmsnorm)
    float* XS  = XN  + 1048576;       // 2,097,152 f
    float* DEL = XS  + 2097152;       // 2,097,152 f  (also Y1 during frontend)
    float* Y   = DEL + 2097152;       // 2,097,152 f
    float* XDB = Y   + 2097152;       // 131,072 f
    float* Y1  = DEL;                 // frontend-only alias
    float* logits = (float*)d_out;
    float* Q   = logits;              // first 1M floats of d_out reused as scan carry
                                      // (head GEMM fully overwrites at the end)

    // ---------------- frontend ----------------
    im2col1_k<<<1280, 256, 0, stream>>>(feats, XZ);
    gemm_f32<1, 2><<<dim3(512 / 64, M1ROWS / 64), 256, 0, stream>>>(
        XZ, 240, c1w, 240, c1b, Y1, 512, M1ROWS, 512, 240);
    im2col2_k<<<(MROWS * 512) / 256, 256, 0, stream>>>(Y1, XZ);
    gemm_f32<1, 2><<<dim3(512 / 64, MROWS / 64), 256, 0, stream>>>(
        XZ, 1536, c2w, 1536, c2b, X, 512, MROWS, 512, 1536);

    // ---------------- mamba blocks ----------------
    for (int blk = 0; blk < NB; ++blk) {
        rmsnorm_k<<<MROWS, 256, 0, stream>>>(X, nw + blk * DMODEL, XN);
        gemm_f32<0, 0><<<dim3(2048 / 64, MROWS / 64), 256, 0, stream>>>(
            XN, 512, ipw + (size_t)blk * 512 * 2048, 2048, nullptr,
            XZ, 2048, MROWS, 2048, 512);
        dwconv_silu_k<<<dim3(4, MROWS), 256, 0, stream>>>(
            XZ, cw + blk * DIN * 4, cb + blk * DIN, XS);
        gemm_f32<0, 0><<<dim3(64 / 64, MROWS / 64), 256, 0, stream>>>(
            XS, 1024, xpw + (size_t)blk * 1024 * 64, 64, nullptr,
            XDB, 64, MROWS, 64, 1024);
        gemm_f32<0, 3><<<dim3(1024 / 64, MROWS / 64), 256, 0, stream>>>(
            XDB, 64, dpw + (size_t)blk * 32 * 1024, 1024, dpb + blk * DIN,
            DEL, 1024, MROWS, 1024, 32);
        // chunked parallel scan (3 dispatches)
        scan_chunk_k<0><<<dim3(16, NCHUNK, BATCH), 256, 0, stream>>>(
            DEL, XS, XDB, XZ, alog + (size_t)blk * DIN * NSTATE,
            dskp + blk * DIN, nullptr, XN, Q, nullptr);
        scan_mid_k<<<256, 256, 0, stream>>>(XN, Q);
        scan_chunk_k<1><<<dim3(16, NCHUNK, BATCH), 256, 0, stream>>>(
            DEL, XS, XDB, XZ, alog + (size_t)blk * DIN * NSTATE,
            dskp + blk * DIN, Q, nullptr, nullptr, Y);
        gemm_f32<0, 4><<<dim3(512 / 64, MROWS / 64), 256, 0, stream>>>(
            Y, 1024, opw + (size_t)blk * 1024 * 512, 512, nullptr,
            X, 512, MROWS, 512, 1024);
    }

    // ---------------- head ----------------
    gemm_f32<0, 1><<<dim3(2048 / 64, MROWS / 64), 256, 0, stream>>>(
        X, 512, hw, 2048, hb, logits, 2048, MROWS, 2048, 512);
    lens_k<<<1, 64, 0, stream>>>(flens, logits + (size_t)MROWS * VOCABSZ);
}

// Round 3
// 1488.989 us; speedup vs baseline: 3.0549x; 1.3520x over previous
//
#include <hip/hip_runtime.h>
#include <hip/hip_bf16.h>

#define DMODEL 512
#define NB 8
#define VOCABSZ 2048
#define MEL 80
#define DIN 1024
#define NSTATE 16
#define DTRANK 32
#define BATCH 4
#define TIN 2048
#define LL1 1024
#define LSEQ 512
#define MROWS (BATCH*LSEQ)    // 2048
#define M1ROWS (BATCH*LL1)    // 4096
#define NCHUNK 16
#define LCHUNK 32

typedef unsigned short u16;
typedef unsigned int   u32;
typedef __attribute__((ext_vector_type(8))) short short8;
typedef __attribute__((ext_vector_type(4))) float f32x4;

__device__ __forceinline__ float bf2f(u16 v) { return __uint_as_float(((u32)v) << 16); }
__device__ __forceinline__ u16 f2bf(float f) {
    u32 u = __float_as_uint(f);
    return (u16)((u + 0x7fffu + ((u >> 16) & 1u)) >> 16);
}
__device__ __forceinline__ float gelu_exact(float v) {
    return 0.5f * v * (1.0f + erff(v * 0.70710678118654752f));
}
__device__ __forceinline__ float silu_f(float v) { return v / (1.0f + __expf(-v)); }
__device__ __forceinline__ float softplus_f(float v) { return v > 20.f ? v : log1pf(__expf(v)); }

// ---------------------------------------------------------------------------
// bf16 MFMA GEMM, m97 structure. C[M,N] = epi(A[M,K] @ BT[N,K]^T + bias)
// A, BT row-major bf16 (u16). BM = WM*MR*16, BN = WN*NR*16, BK = 32.
// EPI: 0 none, 1 +bias, 2 gelu(+bias), 3 softplus(+bias), 4 +=Cf (residual)
// Cf (fp32) and/or Cb (bf16) outputs; either may be null.
// ---------------------------------------------------------------------------
template<int WM, int WN, int MR, int NR, int EPI>
__global__ __launch_bounds__(WM*WN*64) void gemm_bf16(
    const u16* __restrict__ A, int lda,
    const u16* __restrict__ BT, int ldb,
    const float* __restrict__ bias,
    float* __restrict__ Cf, u16* __restrict__ Cb, int ldc,
    int K)
{
    constexpr int BM = WM * MR * 16;
    constexpr int BN = WN * NR * 16;
    constexpr int NT = WM * WN * 64;
    __shared__ __align__(16) u16 As[BM * 32];
    __shared__ __align__(16) u16 Bs[BN * 32];
    const int tid = threadIdx.x;
    const int m0 = blockIdx.y * BM, n0 = blockIdx.x * BN;
    const int lane = tid & 63;
    const int wave = tid >> 6;
    const int wm = wave / WN, wn = wave % WN;
    const int lr = lane & 15, lk = lane >> 4;

    f32x4 acc[MR][NR];
#pragma unroll
    for (int m = 0; m < MR; ++m)
#pragma unroll
        for (int n = 0; n < NR; ++n) acc[m][n] = (f32x4){0.f, 0.f, 0.f, 0.f};

    for (int kt = 0; kt < K; kt += 32) {
#pragma unroll
        for (int c = 0; c < (BM * 4) / NT; ++c) {
            int idx = c * NT + tid;
            const u16* src = A + (size_t)(m0 + (idx >> 2)) * lda + kt + (idx & 3) * 8;
            __builtin_amdgcn_global_load_lds(
                (const __attribute__((address_space(1))) void*)src,
                (__attribute__((address_space(3))) void*)&As[idx * 8], 16, 0, 0);
        }
#pragma unroll
        for (int c = 0; c < (BN * 4) / NT; ++c) {
            int idx = c * NT + tid;
            const u16* src = BT + (size_t)(n0 + (idx >> 2)) * ldb + kt + (idx & 3) * 8;
            __builtin_amdgcn_global_load_lds(
                (const __attribute__((address_space(1))) void*)src,
                (__attribute__((address_space(3))) void*)&Bs[idx * 8], 16, 0, 0);
        }
        __syncthreads();
        short8 a[MR], b[NR];
#pragma unroll
        for (int m = 0; m < MR; ++m)
            a[m] = *(const short8*)&As[((wm * MR + m) * 16 + lr) * 32 + lk * 8];
#pragma unroll
        for (int n = 0; n < NR; ++n)
            b[n] = *(const short8*)&Bs[((wn * NR + n) * 16 + lr) * 32 + lk * 8];
#pragma unroll
        for (int m = 0; m < MR; ++m)
#pragma unroll
            for (int n = 0; n < NR; ++n)
                acc[m][n] = __builtin_amdgcn_mfma_f32_16x16x32_bf16(a[m], b[n], acc[m][n], 0, 0, 0);
        __syncthreads();
    }

#pragma unroll
    for (int m = 0; m < MR; ++m) {
#pragma unroll
        for (int n = 0; n < NR; ++n) {
#pragma unroll
            for (int r = 0; r < 4; ++r) {
                const int row = m0 + (wm * MR + m) * 16 + lk * 4 + r;
                const int col = n0 + (wn * NR + n) * 16 + lr;
                float v = acc[m][n][r];
                if (EPI == 1)      v += bias[col];
                else if (EPI == 2) v = gelu_exact(v + bias[col]);
                else if (EPI == 3) v = softplus_f(v + bias[col]);
                else if (EPI == 4) v += Cf[(size_t)row * ldc + col];
                if (Cf) Cf[(size_t)row * ldc + col] = v;
                if (Cb) Cb[(size_t)row * ldc + col] = f2bf(v);
            }
        }
    }
}

// transpose-cast: in (R,C) fp32 -> out (C,R) bf16; batched over blockIdx.z
__global__ __launch_bounds__(256) void tcast_k(const float* __restrict__ in, u16* __restrict__ out,
                                               int R, int C, size_t sin, size_t sout) {
    in  += (size_t)blockIdx.z * sin;
    out += (size_t)blockIdx.z * sout;
    __shared__ float s[32][33];
    const int tx = threadIdx.x & 31, ty = threadIdx.x >> 5;
    const int r0 = blockIdx.y * 32, c0 = blockIdx.x * 32;
#pragma unroll
    for (int i = 0; i < 4; ++i)
        s[ty + i * 8][tx] = in[(size_t)(r0 + ty + i * 8) * C + c0 + tx];
    __syncthreads();
#pragma unroll
    for (int i = 0; i < 4; ++i)
        out[(size_t)(c0 + ty + i * 8) * R + r0 + tx] = f2bf(s[tx][ty + i * 8]);
}

// strided cast+pad: out[r][c] = c<cin ? in[r*instride+c] : 0 ; batched over z
__global__ void castpad_k(const float* __restrict__ in, u16* __restrict__ out,
                          int rows, int cin, int cout, int instride,
                          size_t sin, size_t sout) {
    in  += (size_t)blockIdx.z * sin;
    out += (size_t)blockIdx.z * sout;
    int idx = blockIdx.x * 256 + threadIdx.x;
    if (idx >= rows * cout) return;
    int c = idx % cout, r = idx / cout;
    out[idx] = (c < cin) ? f2bf(in[(size_t)r * instride + c]) : (u16)0;
}

// im2col for conv1 -> bf16, K padded 240->256
__global__ void im2col1_k(const float* __restrict__ feats, u16* __restrict__ out) {
    int idx = blockIdx.x * 256 + threadIdx.x;       // M1ROWS*256
    int c = idx & 255, m = idx >> 8;
    int l1 = m & (LL1 - 1), b = m >> 10;
    float v = 0.f;
    if (c < 240) {
        int ci = c / 3, kk = c - ci * 3;
        int t = 2 * l1 - 1 + kk;
        if (t >= 0 && t < TIN) v = feats[((size_t)b * TIN + t) * MEL + ci];
    }
    out[idx] = f2bf(v);
}

// im2col for conv2 -> bf16 (2048,1536), reads Y1 fp32
__global__ void im2col2_k(const float* __restrict__ y1, u16* __restrict__ out) {
    int idx = blockIdx.x * 256 + threadIdx.x;       // MROWS*1536
    int c = idx % 1536, m = idx / 1536;
    int l = m & (LSEQ - 1), b = m >> 9;
    int ci = c / 3, kk = c - ci * 3;
    int t = 2 * l - 1 + kk;
    float v = (t >= 0 && t < LL1) ? y1[((size_t)b * LL1 + t) * 512 + ci] : 0.f;
    out[idx] = f2bf(v);
}

// RMSNorm: one block per row of 512; fp32 in, bf16 out
__global__ __launch_bounds__(256) void rmsnorm_k(const float* __restrict__ x,
                                                 const float* __restrict__ nw,
                                                 u16* __restrict__ xn) {
    int m = blockIdx.x;
    int tid = threadIdx.x;
    const float2 v = *reinterpret_cast<const float2*>(&x[(size_t)m * DMODEL + tid * 2]);
    float ss = v.x * v.x + v.y * v.y;
#pragma unroll
    for (int o = 32; o > 0; o >>= 1) ss += __shfl_down(ss, o);
    __shared__ float sred[4];
    __shared__ float sscale;
    if ((tid & 63) == 0) sred[tid >> 6] = ss;
    __syncthreads();
    if (tid == 0) {
        float tot = sred[0] + sred[1] + sred[2] + sred[3];
        sscale = rsqrtf(tot / 512.f + 1e-5f);
    }
    __syncthreads();
    float sc = sscale;
    u32 pack = (u32)f2bf(v.x * sc * nw[tid * 2]) | ((u32)f2bf(v.y * sc * nw[tid * 2 + 1]) << 16);
    *reinterpret_cast<u32*>(&xn[(size_t)m * DMODEL + tid * 2]) = pack;
}

// causal depthwise conv (K=4) + bias + SiLU; bf16 xz in, fp32+bf16 xs out
__global__ __launch_bounds__(256) void dwconv_silu_k(const u16* __restrict__ xzb,
                                                     const float* __restrict__ cw,
                                                     const float* __restrict__ cb,
                                                     float* __restrict__ xs,
                                                     u16* __restrict__ xsb) {
    int d = blockIdx.x * 256 + threadIdx.x;
    int m = blockIdx.y;
    int l = m & (LSEQ - 1);
    int b = m >> 9;
    float acc = cb[d];
    const float4 w4 = *reinterpret_cast<const float4*>(&cw[d * 4]);
    const float wk[4] = {w4.x, w4.y, w4.z, w4.w};
#pragma unroll
    for (int k = 0; k < 4; k++) {
        int t = l - 3 + k;
        if (t >= 0) acc += wk[k] * bf2f(xzb[((size_t)(b * LSEQ + t)) * (2 * DIN) + d]);
    }
    float o = silu_f(acc);
    xs[(size_t)m * DIN + d] = o;
    xsb[(size_t)m * DIN + d] = f2bf(o);
}

// ---------------------------------------------------------------------------
// Chunked parallel scan (as R2) with bf16 delta/z inputs and bf16 y output.
// ---------------------------------------------------------------------------
template<int PASS>
__global__ __launch_bounds__(256) void scan_chunk_k(
    const u16* __restrict__ deltab, const float* __restrict__ xs,
    const float* __restrict__ xdb, const u16* __restrict__ xzb,
    const float* __restrict__ alog, const float* __restrict__ dsk,
    const float* __restrict__ hin,
    float* __restrict__ Pout, float* __restrict__ Qout,
    u16* __restrict__ yb)
{
    __shared__ float s_bc[LCHUNK * 32];
    __shared__ float s_dl[LCHUNK * 64];
    __shared__ float s_xs[LCHUNK * 64];
    __shared__ float s_z [PASS ? LCHUNK * 64 : 1];

    const int tid  = threadIdx.x;
    const int j    = tid & 3;
    const int dsub = tid >> 2;
    const int d0   = blockIdx.x * 64;
    const int c    = blockIdx.y;
    const int b    = blockIdx.z;
    const int d    = d0 + dsub;
    const size_t rbase = (size_t)b * LSEQ + c * LCHUNK;

    for (int idx = tid; idx < LCHUNK * 32; idx += 256) {
        int t = idx >> 5, cc = idx & 31;
        s_bc[idx] = xdb[(rbase + t) * 64 + 32 + cc];
    }
    for (int idx = tid; idx < LCHUNK * 64; idx += 256) {
        int t = idx >> 6, dd = idx & 63;
        s_dl[idx] = bf2f(deltab[(rbase + t) * DIN + d0 + dd]);
        s_xs[idx] = xs[(rbase + t) * DIN + d0 + dd];
        if (PASS) s_z[idx] = bf2f(xzb[(rbase + t) * (2 * DIN) + DIN + d0 + dd]);
    }
    __syncthreads();

    float a[4], h[4];
#pragma unroll
    for (int nj = 0; nj < 4; nj++)
        a[nj] = -__expf(alog[(size_t)d * NSTATE + j * 4 + nj]);

    const size_t chbase = ((size_t)(b * NCHUNK + c) * DIN + d) * NSTATE + j * 4;
    if (PASS) {
        const float4 h4 = *reinterpret_cast<const float4*>(&hin[chbase]);
        h[0] = h4.x; h[1] = h4.y; h[2] = h4.z; h[3] = h4.w;
    } else {
        h[0] = h[1] = h[2] = h[3] = 0.f;
    }
    const float dskv = PASS ? dsk[d] : 0.f;
    float sdl = 0.f;

    for (int t = 0; t < LCHUNK; t++) {
        const float dl = s_dl[t * 64 + dsub];
        const float xv = s_xs[t * 64 + dsub];
        const float dlx = dl * xv;
        if (!PASS) sdl += dl;
        float yv = 0.f;
#pragma unroll
        for (int nj = 0; nj < 4; nj++) {
            const float bn = s_bc[t * 32 + j * 4 + nj];
            const float dA = __expf(dl * a[nj]);
            h[nj] = fmaf(dA, h[nj], dlx * bn);
            if (PASS) {
                const float cn = s_bc[t * 32 + 16 + j * 4 + nj];
                yv = fmaf(h[nj], cn, yv);
            }
        }
        if (PASS) {
            yv += __shfl_xor(yv, 1);
            yv += __shfl_xor(yv, 2);
            if (j == 0) {
                const float zv = s_z[t * 64 + dsub];
                yb[(rbase + t) * DIN + d] = f2bf((yv + xv * dskv) * silu_f(zv));
            }
        }
    }

    if (!PASS) {
        float4 Pv, Qv;
        Pv.x = __expf(a[0] * sdl); Pv.y = __expf(a[1] * sdl);
        Pv.z = __expf(a[2] * sdl); Pv.w = __expf(a[3] * sdl);
        Qv.x = h[0]; Qv.y = h[1]; Qv.z = h[2]; Qv.w = h[3];
        *reinterpret_cast<float4*>(&Pout[chbase]) = Pv;
        *reinterpret_cast<float4*>(&Qout[chbase]) = Qv;
    }
}

__global__ __launch_bounds__(256) void scan_mid_k(const float* __restrict__ P,
                                                  float* __restrict__ Q) {
    const int tid = blockIdx.x * 256 + threadIdx.x;
    const int b  = tid >> 14;
    const int dn = tid & 16383;
    const size_t base = (size_t)b * (NCHUNK * DIN * NSTATE) + dn;
    float p[NCHUNK], q[NCHUNK];
#pragma unroll
    for (int c = 0; c < NCHUNK; c++) {
        p[c] = P[base + (size_t)c * (DIN * NSTATE)];
        q[c] = Q[base + (size_t)c * (DIN * NSTATE)];
    }
    float h = 0.f;
    Q[base] = 0.f;
#pragma unroll
    for (int c = 1; c < NCHUNK; c++) {
        h = fmaf(p[c - 1], h, q[c - 1]);
        Q[base + (size_t)c * (DIN * NSTATE)] = h;
    }
}

__global__ void lens_k(const int* __restrict__ feat_lens, float* __restrict__ out) {
    int b = threadIdx.x;
    if (b < BATCH) {
        int v = feat_lens[b] / 4;
        if (v < 1) v = 1;
        out[b] = (float)v;
    }
}

extern "C" void kernel_launch(void* const* d_in, const int* in_sizes, int n_in,
                              void* d_out, int out_size, void* d_ws, size_t ws_size,
                              hipStream_t stream)
{
    const float* feats = (const float*)d_in[0];
    const int*   flens = (const int*)  d_in[1];
    const float* c1w = (const float*)d_in[2];
    const float* c1b = (const float*)d_in[3];
    const float* c2w = (const float*)d_in[4];
    const float* c2b = (const float*)d_in[5];
    const float* nw  = (const float*)d_in[6];
    const float* ipw = (const float*)d_in[7];
    const float* cw  = (const float*)d_in[8];
    const float* cb  = (const float*)d_in[9];
    const float* xpw = (const float*)d_in[10];
    const float* dpw = (const float*)d_in[11];
    const float* dpb = (const float*)d_in[12];
    const float* alog= (const float*)d_in[13];
    const float* dskp= (const float*)d_in[14];
    const float* opw = (const float*)d_in[15];
    const float* hw  = (const float*)d_in[16];
    const float* hb  = (const float*)d_in[17];

    float* ws = (float*)d_ws;
    u16*  XZb   = (u16*)ws;                       // (2048,2048) bf16; also im2col buf
    float* X    = ws + 2097152;                   // (2048,512) f32
    u16*  XN    = (u16*)(ws + 3145728);           // (2048,512) bf16
    u16*  Xb    = (u16*)(ws + 3670016);           // (2048,512) bf16
    float* XS   = ws + 4194304;                   // (2048,1024) f32 ; Y1 alias in frontend
    u16*  XSb   = (u16*)(ws + 6291456);           // (2048,1024) bf16
    u16*  DELb  = (u16*)(ws + 7340032);           // (2048,1024) bf16
    float* XDB  = ws + 8388608;                   // (2048,64) f32
    float* P    = ws + 8519680;                   // (4,16,1024,16) f32
    u16*  WdT   = (u16*)(ws + 9568256);           // (1024,1024) bf16, per-layer
    u16*  Yb    = (u16*)(ws + 10092544);          // (2048,1024) bf16
    u16*  ipwT  = (u16*)(ws + 11141120);          // (2048,512) bf16, per-layer
    u16*  opwT  = (u16*)(ws + 11665408);          // (512,1024) bf16, per-layer
    u16*  hwT   = (u16*)(ws + 11927552);          // (2048,512) bf16
    u16*  xpwT  = (u16*)(ws + 12451840);          // 8 x (64,1024) bf16
    u16*  dpwT  = (u16*)(ws + 12713984);          // 8 x (1024,32) bf16
    u16*  xpwdt = (u16*)(ws + 12845056);          // 8 x (1024,32) bf16
    u16*  c1wb  = (u16*)(ws + 12976128);          // (512,256) bf16 padded
    u16*  c2wb  = (u16*)(ws + 13041664);          // (512,1536) bf16
    float* Y1   = XS;                             // frontend alias
    float* logits = (float*)d_out;
    float* Q    = logits;                         // first 1M floats of d_out; head overwrites

    // ---------------- weight prep (per launch) ----------------
    castpad_k<<<dim3(512, 1, 1), 256, 0, stream>>>(c1w, c1wb, 512, 240, 256, 240, 0, 0);
    castpad_k<<<dim3(3072, 1, 1), 256, 0, stream>>>(c2w, c2wb, 512, 1536, 1536, 1536, 0, 0);
    tcast_k<<<dim3(64, 16, 1), 256, 0, stream>>>(hw, hwT, 512, 2048, 0, 0);
    tcast_k<<<dim3(2, 32, 8), 256, 0, stream>>>(xpw, xpwT, 1024, 64, 65536, 65536);
    tcast_k<<<dim3(32, 1, 8), 256, 0, stream>>>(dpw, dpwT, 32, 1024, 32768, 32768);
    castpad_k<<<dim3(128, 1, 8), 256, 0, stream>>>(xpw, xpwdt, 1024, 32, 32, 64, 65536, 32768);

    // ---------------- frontend ----------------
    im2col1_k<<<4096, 256, 0, stream>>>(feats, XZb);
    gemm_bf16<2, 2, 4, 4, 2><<<dim3(4, 32), 256, 0, stream>>>(
        XZb, 256, c1wb, 256, c1b, Y1, nullptr, 512, 256);
    im2col2_k<<<12288, 256, 0, stream>>>(Y1, XZb);
    gemm_bf16<2, 2, 4, 4, 2><<<dim3(4, 16), 256, 0, stream>>>(
        XZb, 1536, c2wb, 1536, c2b, X, nullptr, 512, 1536);

    // ---------------- mamba blocks ----------------
    for (int blk = 0; blk < NB; ++blk) {
        tcast_k<<<dim3(64, 16, 1), 256, 0, stream>>>(ipw + (size_t)blk * 1048576, ipwT, 512, 2048, 0, 0);
        tcast_k<<<dim3(16, 32, 1), 256, 0, stream>>>(opw + (size_t)blk * 524288, opwT, 1024, 512, 0, 0);
        // W_deltaT = dpwT @ xpw[:, :32]^T   (1024x1024, K=32)
        gemm_bf16<2, 2, 4, 4, 0><<<dim3(8, 8), 256, 0, stream>>>(
            dpwT + (size_t)blk * 32768, 32, xpwdt + (size_t)blk * 32768, 32,
            nullptr, nullptr, WdT, 1024, 32);
        rmsnorm_k<<<MROWS, 256, 0, stream>>>(X, nw + blk * DMODEL, XN);
        gemm_bf16<2, 2, 4, 4, 0><<<dim3(16, 16), 256, 0, stream>>>(
            XN, 512, ipwT, 512, nullptr, nullptr, XZb, 2048, 512);
        dwconv_silu_k<<<dim3(4, MROWS), 256, 0, stream>>>(
            XZb, cw + blk * DIN * 4, cb + blk * DIN, XS, XSb);
        // xdb = xs @ xpw (N=64, narrow config)
        gemm_bf16<4, 1, 2, 4, 0><<<dim3(1, 16), 256, 0, stream>>>(
            XSb, 1024, xpwT + (size_t)blk * 65536, 1024, nullptr, XDB, nullptr, 64, 1024);
        // delta = softplus(xs @ W_delta + dpb)
        gemm_bf16<2, 2, 4, 4, 3><<<dim3(8, 16), 256, 0, stream>>>(
            XSb, 1024, WdT, 1024, dpb + blk * DIN, nullptr, DELb, 1024, 1024);
        scan_chunk_k<0><<<dim3(16, NCHUNK, BATCH), 256, 0, stream>>>(
            DELb, XS, XDB, nullptr, alog + (size_t)blk * DIN * NSTATE,
            nullptr, nullptr, P, Q, nullptr);
        scan_mid_k<<<256, 256, 0, stream>>>(P, Q);
        scan_chunk_k<1><<<dim3(16, NCHUNK, BATCH), 256, 0, stream>>>(
            DELb, XS, XDB, XZb, alog + (size_t)blk * DIN * NSTATE,
            dskp + blk * DIN, Q, nullptr, nullptr, Yb);
        gemm_bf16<2, 2, 4, 4, 4><<<dim3(4, 16), 256, 0, stream>>>(
            Yb, 1024, opwT, 1024, nullptr, X, Xb, 512, 1024);
    }

    // ---------------- head ----------------
    gemm_bf16<2, 2, 4, 4, 1><<<dim3(16, 16), 256, 0, stream>>>(
        Xb, 512, hwT, 512, hb, logits, nullptr, 2048, 512);
    lens_k<<<1, 64, 0, stream>>>(flens, logits + (size_t)MROWS * VOCABSZ);
}

// Round 4
// 884.675 us; speedup vs baseline: 5.1416x; 1.6831x over previous
//
#include <hip/hip_runtime.h>
#include <hip/hip_bf16.h>

#define DMODEL 512
#define NB 8
#define VOCABSZ 2048
#define MEL 80
#define DIN 1024
#define NSTATE 16
#define DTRANK 32
#define BATCH 4
#define TIN 2048
#define LL1 1024
#define LSEQ 512
#define MROWS (BATCH*LSEQ)    // 2048
#define M1ROWS (BATCH*LL1)    // 4096
#define NCHUNK 16
#define LCHUNK 32

typedef unsigned short u16;
typedef unsigned int   u32;
typedef __attribute__((ext_vector_type(8))) short short8;
typedef __attribute__((ext_vector_type(4))) float f32x4;

__device__ __forceinline__ float bf2f(u16 v) { return __uint_as_float(((u32)v) << 16); }
__device__ __forceinline__ u16 f2bf(float f) {
    u32 u = __float_as_uint(f);
    return (u16)((u + 0x7fffu + ((u >> 16) & 1u)) >> 16);
}
__device__ __forceinline__ float gelu_exact(float v) {
    return 0.5f * v * (1.0f + erff(v * 0.70710678118654752f));
}
__device__ __forceinline__ float silu_f(float v) { return v / (1.0f + __expf(-v)); }
__device__ __forceinline__ float softplus_f(float v) { return v > 20.f ? v : log1pf(__expf(v)); }

// ---------------------------------------------------------------------------
// bf16 MFMA GEMM, 2-phase double-buffered LDS (T3 minimum-2ph recipe):
//   prologue STAGE(buf0); barrier;
//   loop: STAGE(buf^1, next) ; ds_read+MFMA(cur) ; __syncthreads() ; swap.
// C[M,N] = epi(A[M,K] @ BT[N,K]^T + bias).  BM=WM*MR*16, BN=WN*NR*16, BK=32.
// EPI: 0 none, 1 +bias, 2 gelu(+bias), 3 softplus(+bias), 4 +=Cf residual
// SPLITK>1: blockIdx.z owns K/SPLITK slice, writes Cf + z*zstride (EPI must be 0).
// ---------------------------------------------------------------------------
template<int WM, int WN, int MR, int NR, int EPI, int SPLITK>
__global__ __launch_bounds__(WM*WN*64) void gemm2_bf16(
    const u16* __restrict__ A, int lda,
    const u16* __restrict__ BT, int ldb,
    const float* __restrict__ bias,
    float* __restrict__ Cf, u16* __restrict__ Cb, int ldc,
    int K, int zstride)
{
    constexpr int BM = WM * MR * 16;
    constexpr int BN = WN * NR * 16;
    constexpr int NT = WM * WN * 64;
    constexpr int LA = (BM * 4) / NT;
    constexpr int LB = (BN * 4) / NT;
    __shared__ __align__(16) u16 As[2][BM * 32];
    __shared__ __align__(16) u16 Bs[2][BN * 32];
    const int tid = threadIdx.x;
    const int m0 = blockIdx.y * BM, n0 = blockIdx.x * BN;
    const int lane = tid & 63;
    const int wave = tid >> 6;
    const int wm = wave / WN, wn = wave % WN;
    const int lr = lane & 15, lk = lane >> 4;

    int kt0 = 0, kend = K;
    if (SPLITK > 1) {
        const int kb = K / SPLITK;
        kt0 = blockIdx.z * kb;
        kend = kt0 + kb;
        Cf += (size_t)blockIdx.z * zstride;
    }

    f32x4 acc[MR][NR];
#pragma unroll
    for (int m = 0; m < MR; ++m)
#pragma unroll
        for (int n = 0; n < NR; ++n) acc[m][n] = (f32x4){0.f, 0.f, 0.f, 0.f};

    auto stage = [&](int buf, int kt) {
#pragma unroll
        for (int c = 0; c < LA; ++c) {
            int idx = c * NT + tid;
            const u16* src = A + (size_t)(m0 + (idx >> 2)) * lda + kt + (idx & 3) * 8;
            __builtin_amdgcn_global_load_lds(
                (const __attribute__((address_space(1))) void*)src,
                (__attribute__((address_space(3))) void*)&As[buf][idx * 8], 16, 0, 0);
        }
#pragma unroll
        for (int c = 0; c < LB; ++c) {
            int idx = c * NT + tid;
            const u16* src = BT + (size_t)(n0 + (idx >> 2)) * ldb + kt + (idx & 3) * 8;
            __builtin_amdgcn_global_load_lds(
                (const __attribute__((address_space(1))) void*)src,
                (__attribute__((address_space(3))) void*)&Bs[buf][idx * 8], 16, 0, 0);
        }
    };

    stage(0, kt0);
    __syncthreads();
    int cur = 0;
    for (int kt = kt0; kt < kend; kt += 32) {
        if (kt + 32 < kend) stage(cur ^ 1, kt + 32);
        short8 a[MR], b[NR];
#pragma unroll
        for (int m = 0; m < MR; ++m)
            a[m] = *(const short8*)&As[cur][((wm * MR + m) * 16 + lr) * 32 + lk * 8];
#pragma unroll
        for (int n = 0; n < NR; ++n)
            b[n] = *(const short8*)&Bs[cur][((wn * NR + n) * 16 + lr) * 32 + lk * 8];
#pragma unroll
        for (int m = 0; m < MR; ++m)
#pragma unroll
            for (int n = 0; n < NR; ++n)
                acc[m][n] = __builtin_amdgcn_mfma_f32_16x16x32_bf16(a[m], b[n], acc[m][n], 0, 0, 0);
        __syncthreads();
        cur ^= 1;
    }

#pragma unroll
    for (int m = 0; m < MR; ++m) {
#pragma unroll
        for (int n = 0; n < NR; ++n) {
#pragma unroll
            for (int r = 0; r < 4; ++r) {
                const int row = m0 + (wm * MR + m) * 16 + lk * 4 + r;
                const int col = n0 + (wn * NR + n) * 16 + lr;
                float v = acc[m][n][r];
                if (EPI == 1)      v += bias[col];
                else if (EPI == 2) v = gelu_exact(v + bias[col]);
                else if (EPI == 3) v = softplus_f(v + bias[col]);
                else if (EPI == 4) v += Cf[(size_t)row * ldc + col];
                if (Cf) Cf[(size_t)row * ldc + col] = v;
                if (Cb) Cb[(size_t)row * ldc + col] = f2bf(v);
            }
        }
    }
}

// transpose-cast: in (R,C) fp32 -> out (C,R) bf16; batched over blockIdx.z
__global__ __launch_bounds__(256) void tcast_k(const float* __restrict__ in, u16* __restrict__ out,
                                               int R, int C, size_t sin, size_t sout) {
    in  += (size_t)blockIdx.z * sin;
    out += (size_t)blockIdx.z * sout;
    __shared__ float s[32][33];
    const int tx = threadIdx.x & 31, ty = threadIdx.x >> 5;
    const int r0 = blockIdx.y * 32, c0 = blockIdx.x * 32;
#pragma unroll
    for (int i = 0; i < 4; ++i)
        s[ty + i * 8][tx] = in[(size_t)(r0 + ty + i * 8) * C + c0 + tx];
    __syncthreads();
#pragma unroll
    for (int i = 0; i < 4; ++i)
        out[(size_t)(c0 + ty + i * 8) * R + r0 + tx] = f2bf(s[tx][ty + i * 8]);
}

// strided cast+pad: out[r][c] = c<cin ? in[r*instride+c] : 0
__global__ void castpad_k(const float* __restrict__ in, u16* __restrict__ out,
                          int rows, int cin, int cout, int instride,
                          size_t sin, size_t sout) {
    in  += (size_t)blockIdx.z * sin;
    out += (size_t)blockIdx.z * sout;
    int idx = blockIdx.x * 256 + threadIdx.x;
    if (idx >= rows * cout) return;
    int c = idx % cout, r = idx / cout;
    out[idx] = (c < cin) ? f2bf(in[(size_t)r * instride + c]) : (u16)0;
}

// im2col for conv1 -> bf16, K padded 240->256
__global__ void im2col1_k(const float* __restrict__ feats, u16* __restrict__ out) {
    int idx = blockIdx.x * 256 + threadIdx.x;       // M1ROWS*256
    int c = idx & 255, m = idx >> 8;
    int l1 = m & (LL1 - 1), b = m >> 10;
    float v = 0.f;
    if (c < 240) {
        int ci = c / 3, kk = c - ci * 3;
        int t = 2 * l1 - 1 + kk;
        if (t >= 0 && t < TIN) v = feats[((size_t)b * TIN + t) * MEL + ci];
    }
    out[idx] = f2bf(v);
}

// im2col for conv2 -> bf16 (2048,1536)
__global__ void im2col2_k(const float* __restrict__ y1, u16* __restrict__ out) {
    int idx = blockIdx.x * 256 + threadIdx.x;       // MROWS*1536
    int c = idx % 1536, m = idx / 1536;
    int l = m & (LSEQ - 1), b = m >> 9;
    int ci = c / 3, kk = c - ci * 3;
    int t = 2 * l - 1 + kk;
    float v = (t >= 0 && t < LL1) ? y1[((size_t)b * LL1 + t) * 512 + ci] : 0.f;
    out[idx] = f2bf(v);
}

// RMSNorm: one block per row of 512; fp32 in, bf16 out
__global__ __launch_bounds__(256) void rmsnorm_k(const float* __restrict__ x,
                                                 const float* __restrict__ nw,
                                                 u16* __restrict__ xn) {
    int m = blockIdx.x;
    int tid = threadIdx.x;
    const float2 v = *reinterpret_cast<const float2*>(&x[(size_t)m * DMODEL + tid * 2]);
    float ss = v.x * v.x + v.y * v.y;
#pragma unroll
    for (int o = 32; o > 0; o >>= 1) ss += __shfl_down(ss, o);
    __shared__ float sred[4];
    __shared__ float sscale;
    if ((tid & 63) == 0) sred[tid >> 6] = ss;
    __syncthreads();
    if (tid == 0) {
        float tot = sred[0] + sred[1] + sred[2] + sred[3];
        sscale = rsqrtf(tot / 512.f + 1e-5f);
    }
    __syncthreads();
    float sc = sscale;
    u32 pack = (u32)f2bf(v.x * sc * nw[tid * 2]) | ((u32)f2bf(v.y * sc * nw[tid * 2 + 1]) << 16);
    *reinterpret_cast<u32*>(&xn[(size_t)m * DMODEL + tid * 2]) = pack;
}

// causal depthwise conv (K=4) + bias + SiLU; bf16 xz in, fp32+bf16 xs out
__global__ __launch_bounds__(256) void dwconv_silu_k(const u16* __restrict__ xzb,
                                                     const float* __restrict__ cw,
                                                     const float* __restrict__ cb,
                                                     float* __restrict__ xs,
                                                     u16* __restrict__ xsb) {
    int d = blockIdx.x * 256 + threadIdx.x;
    int m = blockIdx.y;
    int l = m & (LSEQ - 1);
    int b = m >> 9;
    float acc = cb[d];
    const float4 w4 = *reinterpret_cast<const float4*>(&cw[d * 4]);
    const float wk[4] = {w4.x, w4.y, w4.z, w4.w};
#pragma unroll
    for (int k = 0; k < 4; k++) {
        int t = l - 3 + k;
        if (t >= 0) acc += wk[k] * bf2f(xzb[((size_t)(b * LSEQ + t)) * (2 * DIN) + d]);
    }
    float o = silu_f(acc);
    xs[(size_t)m * DIN + d] = o;
    xsb[(size_t)m * DIN + d] = f2bf(o);
}

// split-K reduce for x_proj: sum 4 partials -> XDB f32; cols<32 -> dtb bf16
__global__ void xreduce_k(const float* __restrict__ part, float* __restrict__ xdb,
                          u16* __restrict__ dtb) {
    int idx = blockIdx.x * 256 + threadIdx.x;       // 2048*64
    float s = part[idx] + part[131072 + idx] + part[262144 + idx] + part[393216 + idx];
    xdb[idx] = s;
    int c = idx & 63, r = idx >> 6;
    if (c < 32) dtb[r * 32 + c] = f2bf(s);
}

// ---------------------------------------------------------------------------
// Chunked parallel scan (unchanged from R3).
// ---------------------------------------------------------------------------
template<int PASS>
__global__ __launch_bounds__(256) void scan_chunk_k(
    const u16* __restrict__ deltab, const float* __restrict__ xs,
    const float* __restrict__ xdb, const u16* __restrict__ xzb,
    const float* __restrict__ alog, const float* __restrict__ dsk,
    const float* __restrict__ hin,
    float* __restrict__ Pout, float* __restrict__ Qout,
    u16* __restrict__ yb)
{
    __shared__ float s_bc[LCHUNK * 32];
    __shared__ float s_dl[LCHUNK * 64];
    __shared__ float s_xs[LCHUNK * 64];
    __shared__ float s_z [PASS ? LCHUNK * 64 : 1];

    const int tid  = threadIdx.x;
    const int j    = tid & 3;
    const int dsub = tid >> 2;
    const int d0   = blockIdx.x * 64;
    const int c    = blockIdx.y;
    const int b    = blockIdx.z;
    const int d    = d0 + dsub;
    const size_t rbase = (size_t)b * LSEQ + c * LCHUNK;

    for (int idx = tid; idx < LCHUNK * 32; idx += 256) {
        int t = idx >> 5, cc = idx & 31;
        s_bc[idx] = xdb[(rbase + t) * 64 + 32 + cc];
    }
    for (int idx = tid; idx < LCHUNK * 64; idx += 256) {
        int t = idx >> 6, dd = idx & 63;
        s_dl[idx] = bf2f(deltab[(rbase + t) * DIN + d0 + dd]);
        s_xs[idx] = xs[(rbase + t) * DIN + d0 + dd];
        if (PASS) s_z[idx] = bf2f(xzb[(rbase + t) * (2 * DIN) + DIN + d0 + dd]);
    }
    __syncthreads();

    float a[4], h[4];
#pragma unroll
    for (int nj = 0; nj < 4; nj++)
        a[nj] = -__expf(alog[(size_t)d * NSTATE + j * 4 + nj]);

    const size_t chbase = ((size_t)(b * NCHUNK + c) * DIN + d) * NSTATE + j * 4;
    if (PASS) {
        const float4 h4 = *reinterpret_cast<const float4*>(&hin[chbase]);
        h[0] = h4.x; h[1] = h4.y; h[2] = h4.z; h[3] = h4.w;
    } else {
        h[0] = h[1] = h[2] = h[3] = 0.f;
    }
    const float dskv = PASS ? dsk[d] : 0.f;
    float sdl = 0.f;

    for (int t = 0; t < LCHUNK; t++) {
        const float dl = s_dl[t * 64 + dsub];
        const float xv = s_xs[t * 64 + dsub];
        const float dlx = dl * xv;
        if (!PASS) sdl += dl;
        float yv = 0.f;
#pragma unroll
        for (int nj = 0; nj < 4; nj++) {
            const float bn = s_bc[t * 32 + j * 4 + nj];
            const float dA = __expf(dl * a[nj]);
            h[nj] = fmaf(dA, h[nj], dlx * bn);
            if (PASS) {
                const float cn = s_bc[t * 32 + 16 + j * 4 + nj];
                yv = fmaf(h[nj], cn, yv);
            }
        }
        if (PASS) {
            yv += __shfl_xor(yv, 1);
            yv += __shfl_xor(yv, 2);
            if (j == 0) {
                const float zv = s_z[t * 64 + dsub];
                yb[(rbase + t) * DIN + d] = f2bf((yv + xv * dskv) * silu_f(zv));
            }
        }
    }

    if (!PASS) {
        float4 Pv, Qv;
        Pv.x = __expf(a[0] * sdl); Pv.y = __expf(a[1] * sdl);
        Pv.z = __expf(a[2] * sdl); Pv.w = __expf(a[3] * sdl);
        Qv.x = h[0]; Qv.y = h[1]; Qv.z = h[2]; Qv.w = h[3];
        *reinterpret_cast<float4*>(&Pout[chbase]) = Pv;
        *reinterpret_cast<float4*>(&Qout[chbase]) = Qv;
    }
}

__global__ __launch_bounds__(256) void scan_mid_k(const float* __restrict__ P,
                                                  float* __restrict__ Q) {
    const int tid = blockIdx.x * 256 + threadIdx.x;
    const int b  = tid >> 14;
    const int dn = tid & 16383;
    const size_t base = (size_t)b * (NCHUNK * DIN * NSTATE) + dn;
    float p[NCHUNK], q[NCHUNK];
#pragma unroll
    for (int c = 0; c < NCHUNK; c++) {
        p[c] = P[base + (size_t)c * (DIN * NSTATE)];
        q[c] = Q[base + (size_t)c * (DIN * NSTATE)];
    }
    float h = 0.f;
    Q[base] = 0.f;
#pragma unroll
    for (int c = 1; c < NCHUNK; c++) {
        h = fmaf(p[c - 1], h, q[c - 1]);
        Q[base + (size_t)c * (DIN * NSTATE)] = h;
    }
}

__global__ void lens_k(const int* __restrict__ feat_lens, float* __restrict__ out) {
    int b = threadIdx.x;
    if (b < BATCH) {
        int v = feat_lens[b] / 4;
        if (v < 1) v = 1;
        out[b] = (float)v;
    }
}

extern "C" void kernel_launch(void* const* d_in, const int* in_sizes, int n_in,
                              void* d_out, int out_size, void* d_ws, size_t ws_size,
                              hipStream_t stream)
{
    const float* feats = (const float*)d_in[0];
    const int*   flens = (const int*)  d_in[1];
    const float* c1w = (const float*)d_in[2];
    const float* c1b = (const float*)d_in[3];
    const float* c2w = (const float*)d_in[4];
    const float* c2b = (const float*)d_in[5];
    const float* nw  = (const float*)d_in[6];
    const float* ipw = (const float*)d_in[7];
    const float* cw  = (const float*)d_in[8];
    const float* cb  = (const float*)d_in[9];
    const float* xpw = (const float*)d_in[10];
    const float* dpw = (const float*)d_in[11];
    const float* dpb = (const float*)d_in[12];
    const float* alog= (const float*)d_in[13];
    const float* dskp= (const float*)d_in[14];
    const float* opw = (const float*)d_in[15];
    const float* hw  = (const float*)d_in[16];
    const float* hb  = (const float*)d_in[17];

    float* ws = (float*)d_ws;
    u16*  XZb   = (u16*)ws;                       // (2048,2048) bf16; also im2col buf
    float* X    = ws + 2097152;                   // (2048,512) f32
    u16*  XN    = (u16*)(ws + 3145728);           // (2048,512) bf16
    u16*  Xb    = (u16*)(ws + 3670016);           // (2048,512) bf16
    float* XS   = ws + 4194304;                   // (2048,1024) f32 ; Y1 alias
    u16*  XSb   = (u16*)(ws + 6291456);           // (2048,1024) bf16
    u16*  DELb  = (u16*)(ws + 7340032);           // (2048,1024) bf16
    float* XDB  = ws + 8388608;                   // (2048,64) f32
    float* P    = ws + 8519680;                   // (4,16,1024,16) f32
    u16*  dtb   = (u16*)(ws + 9568256);           // (2048,32) bf16
    u16*  Yb    = (u16*)(ws + 9633792);           // (2048,1024) bf16
    float* XDBp = ws + 10682368;                  // 4 x (2048,64) f32 split-K partials
    u16*  ipwT  = (u16*)(ws + 11206656);          // (2048,512) bf16, per-layer
    u16*  opwT  = (u16*)(ws + 11730944);          // (512,1024) bf16, per-layer
    u16*  hwT   = (u16*)(ws + 11993088);          // (2048,512) bf16
    u16*  xpwT  = (u16*)(ws + 12517376);          // 8 x (64,1024) bf16
    u16*  dpwT  = (u16*)(ws + 12779520);          // 8 x (1024,32) bf16
    u16*  c1wb  = (u16*)(ws + 12910592);          // (512,256) bf16 padded
    u16*  c2wb  = (u16*)(ws + 12976128);          // (512,1536) bf16
    float* Y1   = XS;
    float* logits = (float*)d_out;
    float* Q    = logits;                         // 1M floats of d_out; head overwrites

    // ---------------- weight prep (once per launch) ----------------
    castpad_k<<<dim3(512, 1, 1), 256, 0, stream>>>(c1w, c1wb, 512, 240, 256, 240, 0, 0);
    castpad_k<<<dim3(3072, 1, 1), 256, 0, stream>>>(c2w, c2wb, 512, 1536, 1536, 1536, 0, 0);
    tcast_k<<<dim3(64, 16, 1), 256, 0, stream>>>(hw, hwT, 512, 2048, 0, 0);
    tcast_k<<<dim3(2, 32, 8), 256, 0, stream>>>(xpw, xpwT, 1024, 64, 65536, 65536);
    tcast_k<<<dim3(32, 1, 8), 256, 0, stream>>>(dpw, dpwT, 32, 1024, 32768, 32768);

    // ---------------- frontend ----------------
    im2col1_k<<<4096, 256, 0, stream>>>(feats, XZb);
    gemm2_bf16<2, 2, 4, 2, 2, 1><<<dim3(8, 32), 256, 0, stream>>>(
        XZb, 256, c1wb, 256, c1b, Y1, nullptr, 512, 256, 0);
    im2col2_k<<<12288, 256, 0, stream>>>(Y1, XZb);
    gemm2_bf16<2, 2, 2, 2, 2, 1><<<dim3(8, 32), 256, 0, stream>>>(
        XZb, 1536, c2wb, 1536, c2b, X, nullptr, 512, 1536, 0);

    // ---------------- mamba blocks ----------------
    for (int blk = 0; blk < NB; ++blk) {
        tcast_k<<<dim3(64, 16, 1), 256, 0, stream>>>(ipw + (size_t)blk * 1048576, ipwT, 512, 2048, 0, 0);
        tcast_k<<<dim3(16, 32, 1), 256, 0, stream>>>(opw + (size_t)blk * 524288, opwT, 1024, 512, 0, 0);
        rmsnorm_k<<<MROWS, 256, 0, stream>>>(X, nw + blk * DMODEL, XN);
        // in_proj: (2048,2048,512)
        gemm2_bf16<2, 2, 4, 2, 0, 1><<<dim3(32, 16), 256, 0, stream>>>(
            XN, 512, ipwT, 512, nullptr, nullptr, XZb, 2048, 512, 0);
        dwconv_silu_k<<<dim3(4, MROWS), 256, 0, stream>>>(
            XZb, cw + blk * DIN * 4, cb + blk * DIN, XS, XSb);
        // x_proj: (2048,64,1024) split-K x4
        gemm2_bf16<2, 2, 2, 2, 0, 4><<<dim3(1, 32, 4), 256, 0, stream>>>(
            XSb, 1024, xpwT + (size_t)blk * 65536, 1024, nullptr,
            XDBp, nullptr, 64, 1024, 131072);
        xreduce_k<<<512, 256, 0, stream>>>(XDBp, XDB, dtb);
        // dt_proj: (2048,1024,32) + softplus
        gemm2_bf16<2, 2, 4, 2, 3, 1><<<dim3(16, 16), 256, 0, stream>>>(
            dtb, 32, dpwT + (size_t)blk * 32768, 32, dpb + blk * DIN,
            nullptr, DELb, 1024, 32, 0);
        // chunked parallel scan
        scan_chunk_k<0><<<dim3(16, NCHUNK, BATCH), 256, 0, stream>>>(
            DELb, XS, XDB, nullptr, alog + (size_t)blk * DIN * NSTATE,
            nullptr, nullptr, P, Q, nullptr);
        scan_mid_k<<<256, 256, 0, stream>>>(P, Q);
        scan_chunk_k<1><<<dim3(16, NCHUNK, BATCH), 256, 0, stream>>>(
            DELb, XS, XDB, XZb, alog + (size_t)blk * DIN * NSTATE,
            dskp + blk * DIN, Q, nullptr, nullptr, Yb);
        // out_proj: (2048,512,1024) + residual
        gemm2_bf16<2, 2, 2, 2, 4, 1><<<dim3(8, 32), 256, 0, stream>>>(
            Yb, 1024, opwT, 1024, nullptr, X, Xb, 512, 1024, 0);
    }

    // ---------------- head ----------------
    gemm2_bf16<2, 2, 4, 2, 1, 1><<<dim3(32, 16), 256, 0, stream>>>(
        Xb, 512, hwT, 512, hb, logits, nullptr, 2048, 512, 0);
    lens_k<<<1, 64, 0, stream>>>(flens, logits + (size_t)MROWS * VOCABSZ);
}

// Round 5
// 858.591 us; speedup vs baseline: 5.2978x; 1.0304x over previous
//
#include <hip/hip_runtime.h>
#include <hip/hip_bf16.h>

#define DMODEL 512
#define NB 8
#define VOCABSZ 2048
#define MEL 80
#define DIN 1024
#define NSTATE 16
#define DTRANK 32
#define BATCH 4
#define TIN 2048
#define LL1 1024
#define LSEQ 512
#define MROWS (BATCH*LSEQ)    // 2048
#define M1ROWS (BATCH*LL1)    // 4096
#define NCHUNK 16
#define LCHUNK 32

typedef unsigned short u16;
typedef unsigned int   u32;
typedef __attribute__((ext_vector_type(8))) short short8;
typedef __attribute__((ext_vector_type(4))) float f32x4;

__device__ __forceinline__ float bf2f(u16 v) { return __uint_as_float(((u32)v) << 16); }
__device__ __forceinline__ u16 f2bf(float f) {
    u32 u = __float_as_uint(f);
    return (u16)((u + 0x7fffu + ((u >> 16) & 1u)) >> 16);
}
__device__ __forceinline__ float gelu_exact(float v) {
    return 0.5f * v * (1.0f + erff(v * 0.70710678118654752f));
}
__device__ __forceinline__ float silu_f(float v) { return v / (1.0f + __expf(-v)); }
__device__ __forceinline__ float softplus_f(float v) { return v > 20.f ? v : log1pf(__expf(v)); }

// ---------------------------------------------------------------------------
// bf16 MFMA GEMM, 2-phase double-buffered LDS (unchanged from R4).
// ---------------------------------------------------------------------------
template<int WM, int WN, int MR, int NR, int EPI, int SPLITK>
__global__ __launch_bounds__(WM*WN*64) void gemm2_bf16(
    const u16* __restrict__ A, int lda,
    const u16* __restrict__ BT, int ldb,
    const float* __restrict__ bias,
    float* __restrict__ Cf, u16* __restrict__ Cb, int ldc,
    int K, int zstride)
{
    constexpr int BM = WM * MR * 16;
    constexpr int BN = WN * NR * 16;
    constexpr int NT = WM * WN * 64;
    constexpr int LA = (BM * 4) / NT;
    constexpr int LB = (BN * 4) / NT;
    __shared__ __align__(16) u16 As[2][BM * 32];
    __shared__ __align__(16) u16 Bs[2][BN * 32];
    const int tid = threadIdx.x;
    const int m0 = blockIdx.y * BM, n0 = blockIdx.x * BN;
    const int lane = tid & 63;
    const int wave = tid >> 6;
    const int wm = wave / WN, wn = wave % WN;
    const int lr = lane & 15, lk = lane >> 4;

    int kt0 = 0, kend = K;
    if (SPLITK > 1) {
        const int kb = K / SPLITK;
        kt0 = blockIdx.z * kb;
        kend = kt0 + kb;
        Cf += (size_t)blockIdx.z * zstride;
    }

    f32x4 acc[MR][NR];
#pragma unroll
    for (int m = 0; m < MR; ++m)
#pragma unroll
        for (int n = 0; n < NR; ++n) acc[m][n] = (f32x4){0.f, 0.f, 0.f, 0.f};

    auto stage = [&](int buf, int kt) {
#pragma unroll
        for (int c = 0; c < LA; ++c) {
            int idx = c * NT + tid;
            const u16* src = A + (size_t)(m0 + (idx >> 2)) * lda + kt + (idx & 3) * 8;
            __builtin_amdgcn_global_load_lds(
                (const __attribute__((address_space(1))) void*)src,
                (__attribute__((address_space(3))) void*)&As[buf][idx * 8], 16, 0, 0);
        }
#pragma unroll
        for (int c = 0; c < LB; ++c) {
            int idx = c * NT + tid;
            const u16* src = BT + (size_t)(n0 + (idx >> 2)) * ldb + kt + (idx & 3) * 8;
            __builtin_amdgcn_global_load_lds(
                (const __attribute__((address_space(1))) void*)src,
                (__attribute__((address_space(3))) void*)&Bs[buf][idx * 8], 16, 0, 0);
        }
    };

    stage(0, kt0);
    __syncthreads();
    int cur = 0;
    for (int kt = kt0; kt < kend; kt += 32) {
        if (kt + 32 < kend) stage(cur ^ 1, kt + 32);
        short8 a[MR], b[NR];
#pragma unroll
        for (int m = 0; m < MR; ++m)
            a[m] = *(const short8*)&As[cur][((wm * MR + m) * 16 + lr) * 32 + lk * 8];
#pragma unroll
        for (int n = 0; n < NR; ++n)
            b[n] = *(const short8*)&Bs[cur][((wn * NR + n) * 16 + lr) * 32 + lk * 8];
#pragma unroll
        for (int m = 0; m < MR; ++m)
#pragma unroll
            for (int n = 0; n < NR; ++n)
                acc[m][n] = __builtin_amdgcn_mfma_f32_16x16x32_bf16(a[m], b[n], acc[m][n], 0, 0, 0);
        __syncthreads();
        cur ^= 1;
    }

#pragma unroll
    for (int m = 0; m < MR; ++m) {
#pragma unroll
        for (int n = 0; n < NR; ++n) {
#pragma unroll
            for (int r = 0; r < 4; ++r) {
                const int row = m0 + (wm * MR + m) * 16 + lk * 4 + r;
                const int col = n0 + (wn * NR + n) * 16 + lr;
                float v = acc[m][n][r];
                if (EPI == 1)      v += bias[col];
                else if (EPI == 2) v = gelu_exact(v + bias[col]);
                else if (EPI == 3) v = softplus_f(v + bias[col]);
                else if (EPI == 4) v += Cf[(size_t)row * ldc + col];
                if (Cf) Cf[(size_t)row * ldc + col] = v;
                if (Cb) Cb[(size_t)row * ldc + col] = f2bf(v);
            }
        }
    }
}

// transpose-cast: in (R,C) fp32 -> out (C,R) bf16; batched over blockIdx.z
__global__ __launch_bounds__(256) void tcast_k(const float* __restrict__ in, u16* __restrict__ out,
                                               int R, int C, size_t sin, size_t sout) {
    in  += (size_t)blockIdx.z * sin;
    out += (size_t)blockIdx.z * sout;
    __shared__ float s[32][33];
    const int tx = threadIdx.x & 31, ty = threadIdx.x >> 5;
    const int r0 = blockIdx.y * 32, c0 = blockIdx.x * 32;
#pragma unroll
    for (int i = 0; i < 4; ++i)
        s[ty + i * 8][tx] = in[(size_t)(r0 + ty + i * 8) * C + c0 + tx];
    __syncthreads();
#pragma unroll
    for (int i = 0; i < 4; ++i)
        out[(size_t)(c0 + ty + i * 8) * R + r0 + tx] = f2bf(s[tx][ty + i * 8]);
}

// strided cast+pad: out[r][c] = c<cin ? in[r*instride+c] : 0
__global__ void castpad_k(const float* __restrict__ in, u16* __restrict__ out,
                          int rows, int cin, int cout, int instride,
                          size_t sin, size_t sout) {
    in  += (size_t)blockIdx.z * sin;
    out += (size_t)blockIdx.z * sout;
    int idx = blockIdx.x * 256 + threadIdx.x;
    if (idx >= rows * cout) return;
    int c = idx % cout, r = idx / cout;
    out[idx] = (c < cin) ? f2bf(in[(size_t)r * instride + c]) : (u16)0;
}

// im2col for conv1 -> bf16, K padded 240->256
__global__ void im2col1_k(const float* __restrict__ feats, u16* __restrict__ out) {
    int idx = blockIdx.x * 256 + threadIdx.x;       // M1ROWS*256
    int c = idx & 255, m = idx >> 8;
    int l1 = m & (LL1 - 1), b = m >> 10;
    float v = 0.f;
    if (c < 240) {
        int ci = c / 3, kk = c - ci * 3;
        int t = 2 * l1 - 1 + kk;
        if (t >= 0 && t < TIN) v = feats[((size_t)b * TIN + t) * MEL + ci];
    }
    out[idx] = f2bf(v);
}

// im2col for conv2: bf16 in (Y1b), bf16 out (2048,1536)
__global__ void im2col2_k(const u16* __restrict__ y1b, u16* __restrict__ out) {
    int idx = blockIdx.x * 256 + threadIdx.x;       // MROWS*1536
    int c = idx % 1536, m = idx / 1536;
    int l = m & (LSEQ - 1), b = m >> 9;
    int ci = c / 3, kk = c - ci * 3;
    int t = 2 * l - 1 + kk;
    out[idx] = (t >= 0 && t < LL1) ? y1b[((size_t)b * LL1 + t) * 512 + ci] : (u16)0;
}

// RMSNorm: one block per row of 512; fp32 in, bf16 out
__global__ __launch_bounds__(256) void rmsnorm_k(const float* __restrict__ x,
                                                 const float* __restrict__ nw,
                                                 u16* __restrict__ xn) {
    int m = blockIdx.x;
    int tid = threadIdx.x;
    const float2 v = *reinterpret_cast<const float2*>(&x[(size_t)m * DMODEL + tid * 2]);
    float ss = v.x * v.x + v.y * v.y;
#pragma unroll
    for (int o = 32; o > 0; o >>= 1) ss += __shfl_down(ss, o);
    __shared__ float sred[4];
    __shared__ float sscale;
    if ((tid & 63) == 0) sred[tid >> 6] = ss;
    __syncthreads();
    if (tid == 0) {
        float tot = sred[0] + sred[1] + sred[2] + sred[3];
        sscale = rsqrtf(tot / 512.f + 1e-5f);
    }
    __syncthreads();
    float sc = sscale;
    u32 pack = (u32)f2bf(v.x * sc * nw[tid * 2]) | ((u32)f2bf(v.y * sc * nw[tid * 2 + 1]) << 16);
    *reinterpret_cast<u32*>(&xn[(size_t)m * DMODEL + tid * 2]) = pack;
}

// causal depthwise conv (K=4) + bias + SiLU; bf16 in, bf16 out only
__global__ __launch_bounds__(256) void dwconv_silu_k(const u16* __restrict__ xzb,
                                                     const float* __restrict__ cw,
                                                     const float* __restrict__ cb,
                                                     u16* __restrict__ xsb) {
    int d = blockIdx.x * 256 + threadIdx.x;
    int m = blockIdx.y;
    int l = m & (LSEQ - 1);
    int b = m >> 9;
    float acc = cb[d];
    const float4 w4 = *reinterpret_cast<const float4*>(&cw[d * 4]);
    const float wk[4] = {w4.x, w4.y, w4.z, w4.w};
#pragma unroll
    for (int k = 0; k < 4; k++) {
        int t = l - 3 + k;
        if (t >= 0) acc += wk[k] * bf2f(xzb[((size_t)(b * LSEQ + t)) * (2 * DIN) + d]);
    }
    xsb[(size_t)m * DIN + d] = f2bf(silu_f(acc));
}

// split-K reduce for x_proj (vectorized): sum 4 partials -> XDB f32; cols<32 -> dtb bf16
__global__ void xreduce_k(const float* __restrict__ part, float* __restrict__ xdb,
                          u16* __restrict__ dtb) {
    int i4 = blockIdx.x * 256 + threadIdx.x;        // 2048*64/4 = 32768
    const float4 p0 = *(const float4*)&part[i4 * 4];
    const float4 p1 = *(const float4*)&part[131072 + i4 * 4];
    const float4 p2 = *(const float4*)&part[262144 + i4 * 4];
    const float4 p3 = *(const float4*)&part[393216 + i4 * 4];
    float4 s;
    s.x = p0.x + p1.x + p2.x + p3.x;
    s.y = p0.y + p1.y + p2.y + p3.y;
    s.z = p0.z + p1.z + p2.z + p3.z;
    s.w = p0.w + p1.w + p2.w + p3.w;
    *(float4*)&xdb[i4 * 4] = s;
    int c4 = i4 & 15, r = i4 >> 4;                  // 16 float4 per row of 64
    if (c4 < 8) {                                    // first 32 cols
        u32 lo = (u32)f2bf(s.x) | ((u32)f2bf(s.y) << 16);
        u32 hi = (u32)f2bf(s.z) | ((u32)f2bf(s.w) << 16);
        *(u32*)&dtb[r * 32 + c4 * 4]     = lo;
        *(u32*)&dtb[r * 32 + c4 * 4 + 2] = hi;
    }
}

// ---------------------------------------------------------------------------
// Chunked parallel scan.  PASS0: emit P,Q.  PASS1: combine prefix in-kernel,
// then seeded scan with fused +xs*D and *silu(z) epilogue -> y bf16.
// ---------------------------------------------------------------------------
template<int PASS>
__global__ __launch_bounds__(256) void scan_chunk_k(
    const u16* __restrict__ deltab, const u16* __restrict__ xsb,
    const float* __restrict__ xdb, const u16* __restrict__ xzb,
    const float* __restrict__ alog, const float* __restrict__ dsk,
    float* __restrict__ P, float* __restrict__ Q,
    u16* __restrict__ yb)
{
    __shared__ float s_bc[LCHUNK * 32];
    __shared__ float s_dl[LCHUNK * 64];
    __shared__ float s_xs[LCHUNK * 64];
    __shared__ float s_z [PASS ? LCHUNK * 64 : 1];

    const int tid  = threadIdx.x;
    const int j    = tid & 3;
    const int dsub = tid >> 2;
    const int d0   = blockIdx.x * 64;
    const int c    = blockIdx.y;
    const int b    = blockIdx.z;
    const int d    = d0 + dsub;
    const size_t rbase = (size_t)b * LSEQ + c * LCHUNK;

    for (int idx = tid; idx < LCHUNK * 32; idx += 256) {
        int t = idx >> 5, cc = idx & 31;
        s_bc[idx] = xdb[(rbase + t) * 64 + 32 + cc];
    }
    for (int idx = tid; idx < LCHUNK * 64; idx += 256) {
        int t = idx >> 6, dd = idx & 63;
        s_dl[idx] = bf2f(deltab[(rbase + t) * DIN + d0 + dd]);
        s_xs[idx] = bf2f(xsb[(rbase + t) * DIN + d0 + dd]);
        if (PASS) s_z[idx] = bf2f(xzb[(rbase + t) * (2 * DIN) + DIN + d0 + dd]);
    }
    __syncthreads();

    float a[4], h[4];
#pragma unroll
    for (int nj = 0; nj < 4; nj++)
        a[nj] = -__expf(alog[(size_t)d * NSTATE + j * 4 + nj]);

    const size_t chstride = (size_t)DIN * NSTATE;
    const size_t chcol = (size_t)d * NSTATE + j * 4;
    h[0] = h[1] = h[2] = h[3] = 0.f;
    if (PASS) {
        // in-kernel combine: h_in = scan over chunks < c of (P,Q)
        for (int c2 = 0; c2 < c; ++c2) {
            const size_t o = ((size_t)(b * NCHUNK + c2)) * chstride + chcol;
            const float4 Pv = *(const float4*)&P[o];
            const float4 Qv = *(const float4*)&Q[o];
            h[0] = fmaf(Pv.x, h[0], Qv.x);
            h[1] = fmaf(Pv.y, h[1], Qv.y);
            h[2] = fmaf(Pv.z, h[2], Qv.z);
            h[3] = fmaf(Pv.w, h[3], Qv.w);
        }
    }
    const float dskv = PASS ? dsk[d] : 0.f;
    float sdl = 0.f;

    for (int t = 0; t < LCHUNK; t++) {
        const float dl = s_dl[t * 64 + dsub];
        const float xv = s_xs[t * 64 + dsub];
        const float dlx = dl * xv;
        if (!PASS) sdl += dl;
        float yv = 0.f;
#pragma unroll
        for (int nj = 0; nj < 4; nj++) {
            const float bn = s_bc[t * 32 + j * 4 + nj];
            const float dA = __expf(dl * a[nj]);
            h[nj] = fmaf(dA, h[nj], dlx * bn);
            if (PASS) {
                const float cn = s_bc[t * 32 + 16 + j * 4 + nj];
                yv = fmaf(h[nj], cn, yv);
            }
        }
        if (PASS) {
            yv += __shfl_xor(yv, 1);
            yv += __shfl_xor(yv, 2);
            if (j == 0) {
                const float zv = s_z[t * 64 + dsub];
                yb[(rbase + t) * DIN + d] = f2bf((yv + xv * dskv) * silu_f(zv));
            }
        }
    }

    if (!PASS) {
        const size_t o = ((size_t)(b * NCHUNK + c)) * chstride + chcol;
        float4 Pv, Qv;
        Pv.x = __expf(a[0] * sdl); Pv.y = __expf(a[1] * sdl);
        Pv.z = __expf(a[2] * sdl); Pv.w = __expf(a[3] * sdl);
        Qv.x = h[0]; Qv.y = h[1]; Qv.z = h[2]; Qv.w = h[3];
        *(float4*)&P[o] = Pv;
        *(float4*)&Q[o] = Qv;
    }
}

__global__ void lens_k(const int* __restrict__ feat_lens, float* __restrict__ out) {
    int b = threadIdx.x;
    if (b < BATCH) {
        int v = feat_lens[b] / 4;
        if (v < 1) v = 1;
        out[b] = (float)v;
    }
}

extern "C" void kernel_launch(void* const* d_in, const int* in_sizes, int n_in,
                              void* d_out, int out_size, void* d_ws, size_t ws_size,
                              hipStream_t stream)
{
    const float* feats = (const float*)d_in[0];
    const int*   flens = (const int*)  d_in[1];
    const float* c1w = (const float*)d_in[2];
    const float* c1b = (const float*)d_in[3];
    const float* c2w = (const float*)d_in[4];
    const float* c2b = (const float*)d_in[5];
    const float* nw  = (const float*)d_in[6];
    const float* ipw = (const float*)d_in[7];
    const float* cw  = (const float*)d_in[8];
    const float* cb  = (const float*)d_in[9];
    const float* xpw = (const float*)d_in[10];
    const float* dpw = (const float*)d_in[11];
    const float* dpb = (const float*)d_in[12];
    const float* alog= (const float*)d_in[13];
    const float* dskp= (const float*)d_in[14];
    const float* opw = (const float*)d_in[15];
    const float* hw  = (const float*)d_in[16];
    const float* hb  = (const float*)d_in[17];

    float* ws = (float*)d_ws;
    u16*  XZb    = (u16*)ws;                      // (2048,2048) bf16
    float* X     = ws + 2097152;                  // (2048,512) f32
    u16*  XN     = (u16*)(ws + 3145728);          // (2048,512) bf16
    u16*  Xb     = (u16*)(ws + 3670016);          // (2048,512) bf16
    u16*  XSb    = (u16*)(ws + 4194304);          // (2048,1024) bf16
    u16*  DELb   = (u16*)(ws + 5242880);          // (2048,1024) bf16
    float* XDB   = ws + 6291456;                  // (2048,64) f32
    float* P     = ws + 6422528;                  // (4,16,1024,16) f32
    u16*  dtb    = (u16*)(ws + 7471104);          // (2048,32) bf16
    u16*  Yb     = (u16*)(ws + 7503872);          // (2048,1024) bf16
    float* XDBp  = ws + 8552448;                  // 4 x (2048,64) f32
    u16*  ipwTa  = (u16*)(ws + 9076736);          // 8 x (2048,512) bf16
    u16*  opwTa  = (u16*)(ws + 13271040);         // 8 x (512,1024) bf16
    u16*  hwT    = (u16*)(ws + 15368192);         // (2048,512) bf16
    u16*  xpwT   = (u16*)(ws + 15892480);         // 8 x (64,1024) bf16
    u16*  dpwT   = (u16*)(ws + 16154624);         // 8 x (1024,32) bf16
    u16*  c1wb   = (u16*)(ws + 16285696);         // (512,256) bf16
    u16*  c2wb   = (u16*)(ws + 16351232);         // (512,1536) bf16
    u16*  Y1b    = (u16*)(ws + 16744448);         // (4096,512) bf16
    float* logits = (float*)d_out;
    float* Q     = logits;                        // 1M floats of d_out; head overwrites

    // ---------------- weight prep (once, batched) ----------------
    castpad_k<<<dim3(512, 1, 1), 256, 0, stream>>>(c1w, c1wb, 512, 240, 256, 240, 0, 0);
    castpad_k<<<dim3(3072, 1, 1), 256, 0, stream>>>(c2w, c2wb, 512, 1536, 1536, 1536, 0, 0);
    tcast_k<<<dim3(64, 16, 1), 256, 0, stream>>>(hw, hwT, 512, 2048, 0, 0);
    tcast_k<<<dim3(2, 32, 8), 256, 0, stream>>>(xpw, xpwT, 1024, 64, 65536, 65536);
    tcast_k<<<dim3(32, 1, 8), 256, 0, stream>>>(dpw, dpwT, 32, 1024, 32768, 32768);
    tcast_k<<<dim3(64, 16, 8), 256, 0, stream>>>(ipw, ipwTa, 512, 2048, 1048576, 1048576);
    tcast_k<<<dim3(16, 32, 8), 256, 0, stream>>>(opw, opwTa, 1024, 512, 524288, 524288);

    // ---------------- frontend ----------------
    im2col1_k<<<4096, 256, 0, stream>>>(feats, XZb);
    gemm2_bf16<2, 2, 4, 2, 2, 1><<<dim3(8, 32), 256, 0, stream>>>(
        XZb, 256, c1wb, 256, c1b, nullptr, Y1b, 512, 256, 0);
    im2col2_k<<<12288, 256, 0, stream>>>(Y1b, XZb);
    gemm2_bf16<2, 2, 2, 2, 2, 1><<<dim3(8, 32), 256, 0, stream>>>(
        XZb, 1536, c2wb, 1536, c2b, X, nullptr, 512, 1536, 0);

    // ---------------- mamba blocks ----------------
    for (int blk = 0; blk < NB; ++blk) {
        rmsnorm_k<<<MROWS, 256, 0, stream>>>(X, nw + blk * DMODEL, XN);
        // in_proj: (2048,2048,512)
        gemm2_bf16<2, 2, 4, 2, 0, 1><<<dim3(32, 16), 256, 0, stream>>>(
            XN, 512, ipwTa + (size_t)blk * 1048576, 512, nullptr,
            nullptr, XZb, 2048, 512, 0);
        dwconv_silu_k<<<dim3(4, MROWS), 256, 0, stream>>>(
            XZb, cw + blk * DIN * 4, cb + blk * DIN, XSb);
        // x_proj: (2048,64,1024) split-K x4
        gemm2_bf16<2, 2, 2, 2, 0, 4><<<dim3(1, 32, 4), 256, 0, stream>>>(
            XSb, 1024, xpwT + (size_t)blk * 65536, 1024, nullptr,
            XDBp, nullptr, 64, 1024, 131072);
        xreduce_k<<<128, 256, 0, stream>>>(XDBp, XDB, dtb);
        // dt_proj: (2048,1024,32) + softplus
        gemm2_bf16<2, 2, 4, 2, 3, 1><<<dim3(16, 16), 256, 0, stream>>>(
            dtb, 32, dpwT + (size_t)blk * 32768, 32, dpb + blk * DIN,
            nullptr, DELb, 1024, 32, 0);
        // chunked parallel scan (2 dispatches; combine fused into pass1)
        scan_chunk_k<0><<<dim3(16, NCHUNK, BATCH), 256, 0, stream>>>(
            DELb, XSb, XDB, nullptr, alog + (size_t)blk * DIN * NSTATE,
            nullptr, P, Q, nullptr);
        scan_chunk_k<1><<<dim3(16, NCHUNK, BATCH), 256, 0, stream>>>(
            DELb, XSb, XDB, XZb, alog + (size_t)blk * DIN * NSTATE,
            dskp + blk * DIN, P, Q, Yb);
        // out_proj: (2048,512,1024) + residual
        gemm2_bf16<2, 2, 2, 2, 4, 1><<<dim3(8, 32), 256, 0, stream>>>(
            Yb, 1024, opwTa + (size_t)blk * 524288, 1024, nullptr,
            X, Xb, 512, 1024, 0);
    }

    // ---------------- head ----------------
    gemm2_bf16<2, 2, 4, 2, 1, 1><<<dim3(32, 16), 256, 0, stream>>>(
        Xb, 512, hwT, 512, hb, logits, nullptr, 2048, 512, 0);
    lens_k<<<1, 64, 0, stream>>>(flens, logits + (size_t)MROWS * VOCABSZ);
}